// Round 1
// 2255.825 us; speedup vs baseline: 1.1743x; 1.1743x over previous
//
#include <hip/hip_runtime.h>
#include <stdint.h>
#include <math.h>

#pragma clang fp contract(off)

#define NH 32
#define NKVH 8
#define SEQ 2048
#define HD 128
#define SCALING_F 0.08838834764831845f
#define OUT0_N (SEQ*NH*HD)   /* 8388608 */

typedef __attribute__((ext_vector_type(8))) short bf16x8;  // 8 bf16 = 4 VGPRs
typedef __attribute__((ext_vector_type(4))) float f32x4;

// ---------------- threefry2x32 (JAX-compatible) ----------------
__host__ __device__ __forceinline__ void tf2x32(uint32_t k0, uint32_t k1,
    uint32_t x0, uint32_t x1, uint32_t* o0, uint32_t* o1) {
  uint32_t k2 = k0 ^ k1 ^ 0x1BD11BDAu;
  x0 += k0; x1 += k1;
#define TFR(r) { x0 += x1; x1 = (x1 << (r)) | (x1 >> (32 - (r))); x1 ^= x0; }
  TFR(13) TFR(15) TFR(26) TFR(6)
  x0 += k1; x1 += k2 + 1u;
  TFR(17) TFR(29) TFR(16) TFR(24)
  x0 += k2; x1 += k0 + 2u;
  TFR(13) TFR(15) TFR(26) TFR(6)
  x0 += k0; x1 += k1 + 3u;
  TFR(17) TFR(29) TFR(16) TFR(24)
  x0 += k1; x1 += k2 + 4u;
  TFR(13) TFR(15) TFR(26) TFR(6)
  x0 += k2; x1 += k0 + 5u;
#undef TFR
  *o0 = x0; *o1 = x1;
}

__device__ __forceinline__ float tf_uniform(uint32_t k0, uint32_t k1, uint32_t idx) {
  uint32_t a, b;
  tf2x32(k0, k1, 0u, idx, &a, &b);
  uint32_t bits = a ^ b;
  return __uint_as_float((bits >> 9) | 0x3f800000u) - 1.0f;
}

// ---------------- monotone float<->uint for atomic min/max ----------------
__device__ __forceinline__ unsigned fmono(float x) {
  unsigned u = __float_as_uint(x);
  return (u >> 31) ? ~u : (u | 0x80000000u);
}
__device__ __forceinline__ float funmono(unsigned m) {
  return __uint_as_float((m >> 31) ? (m ^ 0x80000000u) : ~m);
}

__device__ __forceinline__ void push_minmax(unsigned* slots, unsigned cm, unsigned cM) {
  volatile unsigned* vs = (volatile unsigned*)slots;
  if (cm < vs[0]) atomicMin(&slots[0], cm);
  if (cM > vs[1]) atomicMax(&slots[1], cM);
}

// bf16 truncation — exact for integer values <= 256 (our only use)
__device__ __forceinline__ unsigned short f2bf(float x) {
  return (unsigned short)(__float_as_uint(x) >> 16);
}

__device__ __forceinline__ float fq_st_i(float x, float lo, float hi, float scale,
                                         float scinv, float u) {
  float c = fminf(fmaxf(x, lo), hi);
  float t = (c - lo) * scinv;
  return floorf(t + u) * scale + lo;
}

// ---------------- tiny kernels ----------------
__global__ void init_ws(unsigned* su) {
  int t = threadIdx.x;
  if (t < 12) su[t] = (t & 1) ? 0u : 0xFFFFFFFFu;
}

// cw stat block stride 8: [lo, hi, scale, lut_thr, inv_scale, _, _, _]
__global__ void finalize_kernel(const unsigned* __restrict__ slots,
                                const float* __restrict__ oldmm,
                                float* __restrict__ outc) {
  if (threadIdx.x == 0) {
    float clo = funmono(slots[0]), chi = funmono(slots[1]);
    float o0 = oldmm[0], o1 = oldmm[1];
    bool fin = isfinite(o0) && isfinite(o1);
    float lo = fin ? (0.9f * o0 + 0.1f * clo) : clo;
    float hi = fin ? (0.9f * o1 + 0.1f * chi) : chi;
    float sc = (hi - lo) / 255.0f;
    outc[0] = lo;
    outc[1] = hi;
    outc[2] = sc;
    outc[3] = 0.02004f * fmaxf(fabsf(lo), fabsf(hi));
    outc[4] = 1.0f / sc;
  }
}

__global__ __launch_bounds__(256) void minmax_kernel(const float4* __restrict__ x,
                                                     int n4, unsigned* __restrict__ slots) {
  float lmin = INFINITY, lmax = -INFINITY;
  for (int i = blockIdx.x * blockDim.x + threadIdx.x; i < n4; i += gridDim.x * blockDim.x) {
    float4 a = x[i];
    lmin = fminf(lmin, fminf(fminf(a.x, a.y), fminf(a.z, a.w)));
    lmax = fmaxf(lmax, fmaxf(fmaxf(a.x, a.y), fmaxf(a.z, a.w)));
  }
  __shared__ unsigned bmin, bmax;
  if (threadIdx.x == 0) { bmin = 0xFFFFFFFFu; bmax = 0u; }
  __syncthreads();
  atomicMin(&bmin, fmono(lmin));
  atomicMax(&bmax, fmono(lmax));
  __syncthreads();
  if (threadIdx.x == 0) push_minmax(slots, bmin, bmax);
}

// ---------------- quantization prepasses (integer grid -> bf16) ----------------
// Q: n = round((clip(q)-lo)/sc) in [0,255], stored exactly as bf16
__global__ __launch_bounds__(256) void quant_q_kernel(const float* __restrict__ q,
    unsigned short* __restrict__ qnb, const float* __restrict__ cw) {
  const float lo = cw[0], hi = cw[1], sc = cw[2];
  int idx = blockIdx.x * 256 + threadIdx.x;
  float4 x = ((const float4*)q)[idx];
  float xa[4] = {x.x, x.y, x.z, x.w};
  ushort4 o;
  unsigned short* op = (unsigned short*)&o;
#pragma unroll
  for (int j = 0; j < 4; ++j) {
    float n = rintf((fminf(fmaxf(xa[j], lo), hi) - lo) / sc);
    op[j] = f2bf(n);
  }
  ((ushort4*)qnb)[idx] = o;
}

// K: z = (|lo+sc*m| >= thr), m' = z*m; plus per-row sums Z=sum(z), M=sum(m')
__global__ __launch_bounds__(256) void quant_k_kernel(const float* __restrict__ k,
    unsigned short* __restrict__ kzb, unsigned short* __restrict__ kmb,
    float* __restrict__ Zk, float* __restrict__ Mk, const float* __restrict__ cw) {
  const float lo = cw[8], hi = cw[9], sc = cw[10], thr = cw[11];
  const int tid = threadIdx.x;
  const int row = blockIdx.x * 8 + (tid >> 5);      // global key row [0, 8*2048)
  const int c4 = (tid & 31) * 4;
  float4 x = *(const float4*)&k[(size_t)row * HD + c4];
  float xa[4] = {x.x, x.y, x.z, x.w};
  ushort4 zo, mo;
  unsigned short* zp = (unsigned short*)&zo;
  unsigned short* mp = (unsigned short*)&mo;
  float zs = 0.f, ms = 0.f;
#pragma unroll
  for (int j = 0; j < 4; ++j) {
    float m = rintf((fminf(fmaxf(xa[j], lo), hi) - lo) / sc);
    float kq = m * sc + lo;
    float z = (fabsf(kq) < thr) ? 0.f : 1.f;
    float mq = z * m;
    zs += z; ms += mq;
    zp[j] = f2bf(z); mp[j] = f2bf(mq);
  }
  *(ushort4*)&kzb[(size_t)row * HD + c4] = zo;
  *(ushort4*)&kmb[(size_t)row * HD + c4] = mo;
#pragma unroll
  for (int off = 16; off > 0; off >>= 1) {
    zs += __shfl_xor(zs, off);
    ms += __shfl_xor(ms, off);
  }
  if ((tid & 31) == 0) { Zk[row] = zs; Mk[row] = ms; }
}

// V: transposed outputs vzT/vmT [kvh][d][kp] so AV B-frags are contiguous-in-kp
__global__ __launch_bounds__(256) void quant_v_kernel(const float* __restrict__ v,
    unsigned short* __restrict__ vzT, unsigned short* __restrict__ vmT,
    const float* __restrict__ cw) {
  const float lo = cw[16], hi = cw[17], sc = cw[18], thr = cw[19];
  const int kvh = blockIdx.y, dg = blockIdx.x;   // dg: 0..31 (4 d's each)
  const int tid = threadIdx.x;
  for (int ch = 0; ch < 8; ++ch) {
    int kp = ch * 256 + tid;
    float4 x = *(const float4*)&v[((size_t)(kvh * SEQ + kp)) * HD + dg * 4];
    float xa[4] = {x.x, x.y, x.z, x.w};
#pragma unroll
    for (int j = 0; j < 4; ++j) {
      float m = rintf((fminf(fmaxf(xa[j], lo), hi) - lo) / sc);
      float vq = m * sc + lo;
      float z = (fabsf(vq) < thr) ? 0.f : 1.f;
      float mq = z * m;
      size_t o = ((size_t)(kvh * HD + dg * 4 + j)) * SEQ + kp;
      vzT[o] = f2bf(z);
      vmT[o] = f2bf(mq);
    }
  }
}

// ---------------- QK raw (fp32, min/max only): 128x128 tile, 8x8/thread ----------------
__global__ __launch_bounds__(256, 4) void qk_raw_kernel(
    const float* __restrict__ q, const float* __restrict__ k,
    unsigned* __restrict__ slots) {
  __shared__ float qs[32 * 132], ks[32 * 132];
  const int tid = threadIdx.x;
  const int h = blockIdx.z, qb = blockIdx.y * 128, kb = blockIdx.x * 128;
  const int kvh = h >> 2;
  const float* qg = q + ((size_t)h * SEQ + qb) * HD;
  const float* kg = k + ((size_t)kvh * SEQ + kb) * HD;
  const int tx = tid & 15, ty = tid >> 4;
  const int srow = tid >> 3, sdq = (tid & 7) * 4;
  float acc[8][8];
#pragma unroll
  for (int i = 0; i < 8; ++i)
#pragma unroll
    for (int j = 0; j < 8; ++j) acc[i][j] = 0.f;

  for (int c = 0; c < 4; ++c) {
    __syncthreads();
#pragma unroll
    for (int p = 0; p < 4; ++p) {
      const int row = srow + p * 32;
      const float4 a4 = *(const float4*)&qg[(size_t)row * HD + c * 32 + sdq];
      const float4 b4 = *(const float4*)&kg[(size_t)row * HD + c * 32 + sdq];
      qs[(sdq + 0) * 132 + row] = a4.x;
      qs[(sdq + 1) * 132 + row] = a4.y;
      qs[(sdq + 2) * 132 + row] = a4.z;
      qs[(sdq + 3) * 132 + row] = a4.w;
      ks[(sdq + 0) * 132 + row] = b4.x;
      ks[(sdq + 1) * 132 + row] = b4.y;
      ks[(sdq + 2) * 132 + row] = b4.z;
      ks[(sdq + 3) * 132 + row] = b4.w;
    }
    __syncthreads();
#pragma unroll 4
    for (int dd = 0; dd < 32; ++dd) {
      float a[8], b[8];
      *(float4*)&a[0] = *(const float4*)&qs[dd * 132 + ty * 8];
      *(float4*)&a[4] = *(const float4*)&qs[dd * 132 + ty * 8 + 4];
      *(float4*)&b[0] = *(const float4*)&ks[dd * 132 + tx * 8];
      *(float4*)&b[4] = *(const float4*)&ks[dd * 132 + tx * 8 + 4];
#pragma unroll
      for (int i = 0; i < 8; ++i)
#pragma unroll
        for (int j = 0; j < 8; ++j)
          acc[i][j] = fmaf(a[i], b[j], acc[i][j]);
    }
  }
  float lmin = INFINITY, lmax = -INFINITY;
#pragma unroll
  for (int i = 0; i < 8; ++i)
#pragma unroll
    for (int j = 0; j < 8; ++j) {
      const float rv = acc[i][j] * SCALING_F;
      lmin = fminf(lmin, rv);
      lmax = fmaxf(lmax, rv);
    }
  __shared__ unsigned bmin, bmax;
  if (tid == 0) { bmin = 0xFFFFFFFFu; bmax = 0u; }
  __syncthreads();
  atomicMin(&bmin, fmono(lmin));
  atomicMax(&bmax, fmono(lmax));
  __syncthreads();
  if (tid == 0) push_minmax(slots, bmin, bmax);
}

// ---------------- QK quant (bf16 MFMA, exact integer grid) ----------------
// out = qlo*(klo*Z + ksc*M) + qsc*(klo*P + ksc*R); P=sum n*z, R=sum n*m' over d
// wave w owns rows [qb+w*32, +32); lower-triangular 128-blocks only
__global__ __launch_bounds__(256, 2) void qk_quant_kernel(
    const unsigned short* __restrict__ qnb, const unsigned short* __restrict__ kzb,
    const unsigned short* __restrict__ kmb, const float* __restrict__ Zk,
    const float* __restrict__ Mk, float* __restrict__ qdot,
    const float* __restrict__ cw) {
  const int kbi = blockIdx.x, qbi = blockIdx.y, h = blockIdx.z;
  if (kbi > qbi) return;            // raw-only region above the diagonal
  const int kvh = h >> 2;
  const float qlo = cw[0], qsc = cw[2];
  const float klo = cw[8], ksc = cw[10];
  const int tid = threadIdx.x;
  const int wid = tid >> 6, lane = tid & 63;
  const int fr = lane & 15, fg = lane >> 4;
  const int qrow0 = qbi * 128 + wid * 32;
  const int kcol0 = kbi * 128;
  const unsigned short* qg = qnb + (size_t)h * SEQ * HD;
  const unsigned short* zg = kzb + (size_t)kvh * SEQ * HD;
  const unsigned short* mg = kmb + (size_t)kvh * SEQ * HD;
  f32x4 P[2][8], R[2][8];
  const f32x4 z4 = {0.f, 0.f, 0.f, 0.f};
#pragma unroll
  for (int rg = 0; rg < 2; ++rg)
#pragma unroll
    for (int cg = 0; cg < 8; ++cg) { P[rg][cg] = z4; R[rg][cg] = z4; }

#pragma unroll
  for (int ks = 0; ks < 4; ++ks) {
    const int d0 = ks * 32 + fg * 8;
    const bf16x8 a0 = *(const bf16x8*)&qg[(size_t)(qrow0 + fr) * HD + d0];
    const bf16x8 a1 = *(const bf16x8*)&qg[(size_t)(qrow0 + 16 + fr) * HD + d0];
#pragma unroll
    for (int cg = 0; cg < 8; ++cg) {
      const size_t boff = (size_t)(kcol0 + cg * 16 + fr) * HD + d0;
      const bf16x8 bz = *(const bf16x8*)&zg[boff];
      const bf16x8 bm = *(const bf16x8*)&mg[boff];
      P[0][cg] = __builtin_amdgcn_mfma_f32_16x16x32_bf16(a0, bz, P[0][cg], 0, 0, 0);
      P[1][cg] = __builtin_amdgcn_mfma_f32_16x16x32_bf16(a1, bz, P[1][cg], 0, 0, 0);
      R[0][cg] = __builtin_amdgcn_mfma_f32_16x16x32_bf16(a0, bm, R[0][cg], 0, 0, 0);
      R[1][cg] = __builtin_amdgcn_mfma_f32_16x16x32_bf16(a1, bm, R[1][cg], 0, 0, 0);
    }
  }
#pragma unroll
  for (int cg = 0; cg < 8; ++cg) {
    const int col = kcol0 + cg * 16 + fr;
    const float Z = Zk[kvh * SEQ + col], M = Mk[kvh * SEQ + col];
    const float base = qlo * (klo * Z + ksc * M);
#pragma unroll
    for (int rg = 0; rg < 2; ++rg)
#pragma unroll
      for (int r = 0; r < 4; ++r) {
        const int row = qrow0 + rg * 16 + fg * 4 + r;
        qdot[((size_t)h * SEQ + row) * SEQ + col] =
            base + qsc * (klo * P[rg][cg][r] + ksc * R[rg][cg][r]);
      }
  }
}

// ---------------- softmax: causal skip + stoch-quant + softmax ----------------
__global__ __launch_bounds__(256) void softmax_kernel(
    float* __restrict__ attn, const float* __restrict__ cw,
    unsigned* __restrict__ slots, uint32_t uk0, uint32_t uk1) {
  const int row = blockIdx.x;          // h*SEQ + qi
  const int qi = row & (SEQ - 1);
  const int tid = threadIdx.x;
  const float lo = cw[24], hi = cw[25], sc = cw[26], sci = cw[28];
  float* prow = attn + (size_t)row * SEQ;
  const uint32_t jbase = (uint32_t)row << 11;

  float vals[8];
  float lmax = -INFINITY;
#pragma unroll
  for (int m = 0; m < 2; ++m) {
    int ki = m * 1024 + tid * 4;
    if (ki <= qi) {
      float4 x4 = *(const float4*)&prow[ki];
      float xa[4] = {x4.x, x4.y, x4.z, x4.w};
#pragma unroll
      for (int j = 0; j < 4; ++j) {
        if (ki + j <= qi) {
          float u = tf_uniform(uk0, uk1, jbase + (uint32_t)(ki + j));
          float lg = fq_st_i(xa[j], lo, hi, sc, sci, u) * SCALING_F;
          vals[m * 4 + j] = lg;
          lmax = fmaxf(lmax, lg);
        } else {
          vals[m * 4 + j] = -INFINITY;
        }
      }
    } else {
      vals[m * 4 + 0] = vals[m * 4 + 1] = vals[m * 4 + 2] = vals[m * 4 + 3] = -INFINITY;
    }
  }

  __shared__ float smax[4], ssum[4], smn[4], smx[4];
#pragma unroll
  for (int off = 32; off > 0; off >>= 1) lmax = fmaxf(lmax, __shfl_xor(lmax, off));
  if ((tid & 63) == 0) smax[tid >> 6] = lmax;
  __syncthreads();
  float rmax = fmaxf(fmaxf(smax[0], smax[1]), fmaxf(smax[2], smax[3]));

  float lsum = 0.f;
#pragma unroll
  for (int e = 0; e < 8; ++e) { vals[e] = __expf(vals[e] - rmax); lsum += vals[e]; }
#pragma unroll
  for (int off = 32; off > 0; off >>= 1) lsum += __shfl_xor(lsum, off);
  if ((tid & 63) == 0) ssum[tid >> 6] = lsum;
  __syncthreads();
  float rinv = 1.0f / (ssum[0] + ssum[1] + ssum[2] + ssum[3]);

  float lmin2 = INFINITY, lmax2 = -INFINITY;
#pragma unroll
  for (int m = 0; m < 2; ++m) {
    int ki = m * 1024 + tid * 4;
    float4 st;
    float* stp = (float*)&st;
#pragma unroll
    for (int j = 0; j < 4; ++j) {
      float w = vals[m * 4 + j] * rinv;
      stp[j] = w;
      lmin2 = fminf(lmin2, w);
      lmax2 = fmaxf(lmax2, w);
    }
    *(float4*)&prow[ki] = st;
  }
#pragma unroll
  for (int off = 32; off > 0; off >>= 1) {
    lmin2 = fminf(lmin2, __shfl_xor(lmin2, off));
    lmax2 = fmaxf(lmax2, __shfl_xor(lmax2, off));
  }
  if ((tid & 63) == 0) { smn[tid >> 6] = lmin2; smx[tid >> 6] = lmax2; }
  __syncthreads();
  if (tid == 0) {
    float mn = fminf(fminf(smn[0], smn[1]), fminf(smn[2], smn[3]));
    float mx = fmaxf(fmaxf(smx[0], smx[1]), fmaxf(smx[2], smx[3]));
    push_minmax(slots, fmono(mn), fmono(mx));
  }
}

// ---------------- AV raw (fp32, min/max only): 128x128 tile, 8x8/thread ----------------
__global__ __launch_bounds__(256, 4) void av_raw_kernel(
    const float* __restrict__ attn, const float* __restrict__ v,
    unsigned* __restrict__ slots) {
  __shared__ float as_[32 * 132], vs_[32 * 132];
  const int tid = threadIdx.x;
  const int qbi = (int)gridDim.x - 1 - (int)blockIdx.x;  // largest blocks first
  const int h = blockIdx.y, kvh = h >> 2, qb = qbi * 128;
  const float* ag = attn + ((size_t)h * SEQ + qb) * SEQ;
  const float* vg = v + (size_t)kvh * SEQ * HD;
  const int tx = tid & 15, ty = tid >> 4;
  const int srow = tid >> 3, skq = (tid & 7) * 4;
  const int vkp = tid >> 5, vdp = (tid & 31) * 4;
  float acc[8][8];
#pragma unroll
  for (int i = 0; i < 8; ++i)
#pragma unroll
    for (int j = 0; j < 8; ++j) acc[i][j] = 0.f;

  const int cmax = 4 * qbi + 4;   // attn cols beyond qb+127 are exactly 0
  for (int c = 0; c < cmax; ++c) {
    __syncthreads();
#pragma unroll
    for (int p = 0; p < 4; ++p) {
      const int row = srow + p * 32;
      const float4 a4 = *(const float4*)&ag[(size_t)row * SEQ + c * 32 + skq];
      as_[(skq + 0) * 132 + row] = a4.x;
      as_[(skq + 1) * 132 + row] = a4.y;
      as_[(skq + 2) * 132 + row] = a4.z;
      as_[(skq + 3) * 132 + row] = a4.w;
    }
#pragma unroll
    for (int p = 0; p < 4; ++p) {
      const int kp = vkp + p * 8;
      const float4 v4 = *(const float4*)&vg[(size_t)(c * 32 + kp) * HD + vdp];
      *(float4*)&vs_[kp * 132 + vdp] = v4;
    }
    __syncthreads();
#pragma unroll 4
    for (int kk = 0; kk < 32; ++kk) {
      float a[8], b[8];
      *(float4*)&a[0] = *(const float4*)&as_[kk * 132 + ty * 8];
      *(float4*)&a[4] = *(const float4*)&as_[kk * 132 + ty * 8 + 4];
      *(float4*)&b[0] = *(const float4*)&vs_[kk * 132 + tx * 8];
      *(float4*)&b[4] = *(const float4*)&vs_[kk * 132 + tx * 8 + 4];
#pragma unroll
      for (int i = 0; i < 8; ++i)
#pragma unroll
        for (int j = 0; j < 8; ++j)
          acc[i][j] = fmaf(a[i], b[j], acc[i][j]);
    }
  }
  float lmin = INFINITY, lmax = -INFINITY;
#pragma unroll
  for (int i = 0; i < 8; ++i)
#pragma unroll
    for (int j = 0; j < 8; ++j) {
      lmin = fminf(lmin, acc[i][j]);
      lmax = fmaxf(lmax, acc[i][j]);
    }
  __shared__ unsigned bmin, bmax;
  if (tid == 0) { bmin = 0xFFFFFFFFu; bmax = 0u; }
  __syncthreads();
  atomicMin(&bmin, fmono(lmin));
  atomicMax(&bmax, fmono(lmax));
  __syncthreads();
  if (tid == 0) push_minmax(slots, bmin, bmax);
}

// ---------------- AV quant (bf16 MFMA): out = asc*(vlo*P + vsc*R) ----------------
// A-frags: quantize attn to n in [0,255] on the fly (alo==0 path, as before);
// B-frags: precomputed transposed vzT/vmT. Writes out0 in [S,H,D] layout.
__device__ __forceinline__ bf16x8 pack_a8(const float* __restrict__ ar,
                                          float lo, float hi, float sc) {
  float4 w0 = *(const float4*)ar;
  float4 w1 = *(const float4*)(ar + 4);
  float wa[8] = {w0.x, w0.y, w0.z, w0.w, w1.x, w1.y, w1.z, w1.w};
  bf16x8 r;
#pragma unroll
  for (int j = 0; j < 8; ++j) {
    float n = rintf((fminf(fmaxf(wa[j], lo), hi) - lo) / sc);
    r[j] = (short)(__float_as_uint(n) >> 16);
  }
  return r;
}

__global__ __launch_bounds__(256, 2) void av_quant_kernel(
    const float* __restrict__ attn, const unsigned short* __restrict__ vzT,
    const unsigned short* __restrict__ vmT, float* __restrict__ out0,
    const float* __restrict__ cw) {
  const int qbi = (int)gridDim.x - 1 - (int)blockIdx.x;
  const int h = blockIdx.y, kvh = h >> 2;
  const float alo = cw[32], ahi = cw[33], asc = cw[34];
  const float vlo = cw[16], vsc = cw[18];
  const int tid = threadIdx.x;
  const int wid = tid >> 6, lane = tid & 63;
  const int fr = lane & 15, fg = lane >> 4;
  const int qrow0 = qbi * 128 + wid * 32;
  const float* ag = attn + (size_t)h * SEQ * SEQ;
  const unsigned short* zg = vzT + (size_t)kvh * HD * SEQ;
  const unsigned short* mg = vmT + (size_t)kvh * HD * SEQ;
  const int nk = 4 * (qbi + 1);
  f32x4 P[2][8], R[2][8];
  const f32x4 z4 = {0.f, 0.f, 0.f, 0.f};
#pragma unroll
  for (int rg = 0; rg < 2; ++rg)
#pragma unroll
    for (int cg = 0; cg < 8; ++cg) { P[rg][cg] = z4; R[rg][cg] = z4; }

  for (int ks = 0; ks < nk; ++ks) {
    const int kp0 = ks * 32 + fg * 8;
    const bf16x8 a0 = pack_a8(ag + (size_t)(qrow0 + fr) * SEQ + kp0, alo, ahi, asc);
    const bf16x8 a1 = pack_a8(ag + (size_t)(qrow0 + 16 + fr) * SEQ + kp0, alo, ahi, asc);
#pragma unroll
    for (int cg = 0; cg < 8; ++cg) {
      const size_t boff = (size_t)(cg * 16 + fr) * SEQ + kp0;
      const bf16x8 bz = *(const bf16x8*)&zg[boff];
      const bf16x8 bm = *(const bf16x8*)&mg[boff];
      P[0][cg] = __builtin_amdgcn_mfma_f32_16x16x32_bf16(a0, bz, P[0][cg], 0, 0, 0);
      P[1][cg] = __builtin_amdgcn_mfma_f32_16x16x32_bf16(a1, bz, P[1][cg], 0, 0, 0);
      R[0][cg] = __builtin_amdgcn_mfma_f32_16x16x32_bf16(a0, bm, R[0][cg], 0, 0, 0);
      R[1][cg] = __builtin_amdgcn_mfma_f32_16x16x32_bf16(a1, bm, R[1][cg], 0, 0, 0);
    }
  }
#pragma unroll
  for (int cg = 0; cg < 8; ++cg) {
    const int dcol = cg * 16 + fr;
#pragma unroll
    for (int rg = 0; rg < 2; ++rg)
#pragma unroll
      for (int r = 0; r < 4; ++r) {
        const int row = qrow0 + rg * 16 + fg * 4 + r;
        out0[((size_t)row * NH + h) * HD + dcol] =
            asc * (vlo * P[rg][cg][r] + vsc * R[rg][cg][r]);
      }
  }
}

// ---------------- final elementwise stochastic quantization of out0 ----------------
__global__ __launch_bounds__(256) void stoch_kernel(float* __restrict__ out0,
                                                    const float* __restrict__ cw,
                                                    uint32_t uk0, uint32_t uk1) {
  int idx = blockIdx.x * 256 + threadIdx.x;
  const float lo = cw[40], hi = cw[41], sc = cw[42], sci = cw[44];
  int qi = idx >> 12;                 // / (NH*HD)
  int rem = idx & 4095;
  int h = rem >> 7, d = rem & 127;
  uint32_t j = ((uint32_t)h * SEQ + (uint32_t)qi) * HD + (uint32_t)d;  // BHSD flat
  float x = out0[idx];
  float u = tf_uniform(uk0, uk1, j);
  out0[idx] = fq_st_i(x, lo, hi, sc, sci, u);
}

// ---------------- launcher ----------------
extern "C" void kernel_launch(void* const* d_in, const int* in_sizes, int n_in,
                              void* d_out, int out_size, void* d_ws, size_t ws_size,
                              hipStream_t stream) {
  (void)in_sizes; (void)n_in; (void)out_size; (void)ws_size;
  const float* q      = (const float*)d_in[0];
  const float* k      = (const float*)d_in[1];
  const float* v      = (const float*)d_in[2];
  const float* q_old  = (const float*)d_in[4];
  const float* k_old  = (const float*)d_in[5];
  const float* qk_old = (const float*)d_in[6];
  const float* a_old  = (const float*)d_in[7];
  const float* v_old  = (const float*)d_in[8];
  const float* av_old = (const float*)d_in[9];
  float* out0 = (float*)d_out;
  float* out1 = out0 + (size_t)OUT0_N;
  unsigned* su = (unsigned*)d_ws;
  float* cw = (float*)d_ws + 16;

  // ws scratch (persists across av_quant): vzT/vmT, 8.4 MB total
  unsigned short* vzT = (unsigned short*)((char*)d_ws + 1024);
  unsigned short* vmT = vzT + (size_t)NKVH * SEQ * HD;

  // scratch staged inside the out0 region (all consumers finish before
  // av_quant overwrites out0): qnb(16MB) kzb(4MB) kmb(4MB) Zk Mk  (~25.3MB < 32MB)
  unsigned short* qnb = (unsigned short*)out0;
  unsigned short* kzb = qnb + (size_t)NH * SEQ * HD;
  unsigned short* kmb = kzb + (size_t)NKVH * SEQ * HD;
  float* Zk = (float*)(kmb + (size_t)NKVH * SEQ * HD);
  float* Mk = Zk + NKVH * SEQ;

  uint32_t kq0, kq1, ka0, ka1;
  tf2x32(0u, 0u, 0u, 0u, &kq0, &kq1);
  tf2x32(0u, 0u, 0u, 1u, &ka0, &ka1);

  init_ws<<<1, 32, 0, stream>>>(su);
  minmax_kernel<<<1024, 256, 0, stream>>>((const float4*)q, (NH * SEQ * HD) / 4, su + 0);
  minmax_kernel<<<512, 256, 0, stream>>>((const float4*)k, (NKVH * SEQ * HD) / 4, su + 2);
  minmax_kernel<<<512, 256, 0, stream>>>((const float4*)v, (NKVH * SEQ * HD) / 4, su + 4);
  finalize_kernel<<<1, 1, 0, stream>>>(su + 0, q_old, cw + 0);
  finalize_kernel<<<1, 1, 0, stream>>>(su + 2, k_old, cw + 8);
  finalize_kernel<<<1, 1, 0, stream>>>(su + 4, v_old, cw + 16);

  quant_q_kernel<<<(NH * SEQ * HD) / 4 / 256, 256, 0, stream>>>(q, qnb, cw);
  quant_k_kernel<<<(NKVH * SEQ) / 8, 256, 0, stream>>>(k, kzb, kmb, Zk, Mk, cw);
  quant_v_kernel<<<dim3(32, NKVH), 256, 0, stream>>>(v, vzT, vmT, cw);

  qk_raw_kernel<<<dim3(16, 16, NH), 256, 0, stream>>>(q, k, su + 6);
  finalize_kernel<<<1, 1, 0, stream>>>(su + 6, qk_old, cw + 24);
  qk_quant_kernel<<<dim3(16, 16, NH), 256, 0, stream>>>(qnb, kzb, kmb, Zk, Mk, out1, cw);

  softmax_kernel<<<NH * SEQ, 256, 0, stream>>>(out1, cw, su + 8, kq0, kq1);
  finalize_kernel<<<1, 1, 0, stream>>>(su + 8, a_old, cw + 32);

  av_raw_kernel<<<dim3(16, NH), 256, 0, stream>>>(out1, v, su + 10);
  finalize_kernel<<<1, 1, 0, stream>>>(su + 10, av_old, cw + 40);
  av_quant_kernel<<<dim3(16, NH), 256, 0, stream>>>(out1, vzT, vmT, out0, cw);

  stoch_kernel<<<OUT0_N / 256, 256, 0, stream>>>(out0, cw, ka0, ka1);
}

// Round 2
// 2194.443 us; speedup vs baseline: 1.2072x; 1.0280x over previous
//
#include <hip/hip_runtime.h>
#include <stdint.h>
#include <math.h>

#pragma clang fp contract(off)

#define NH 32
#define NKVH 8
#define SEQ 2048
#define HD 128
#define SCALING_F 0.08838834764831845f
#define OUT0_N (SEQ*NH*HD)   /* 8388608 */

typedef __attribute__((ext_vector_type(8))) short bf16x8;      // 8 bf16 = 4 VGPRs
typedef __attribute__((ext_vector_type(8))) _Float16 f16x8;    // 8 f16  = 4 VGPRs
typedef __attribute__((ext_vector_type(4))) float f32x4;

// ---------------- threefry2x32 (JAX-compatible) ----------------
__host__ __device__ __forceinline__ void tf2x32(uint32_t k0, uint32_t k1,
    uint32_t x0, uint32_t x1, uint32_t* o0, uint32_t* o1) {
  uint32_t k2 = k0 ^ k1 ^ 0x1BD11BDAu;
  x0 += k0; x1 += k1;
#define TFR(r) { x0 += x1; x1 = (x1 << (r)) | (x1 >> (32 - (r))); x1 ^= x0; }
  TFR(13) TFR(15) TFR(26) TFR(6)
  x0 += k1; x1 += k2 + 1u;
  TFR(17) TFR(29) TFR(16) TFR(24)
  x0 += k2; x1 += k0 + 2u;
  TFR(13) TFR(15) TFR(26) TFR(6)
  x0 += k0; x1 += k1 + 3u;
  TFR(17) TFR(29) TFR(16) TFR(24)
  x0 += k1; x1 += k2 + 4u;
  TFR(13) TFR(15) TFR(26) TFR(6)
  x0 += k2; x1 += k0 + 5u;
#undef TFR
  *o0 = x0; *o1 = x1;
}

__device__ __forceinline__ float tf_uniform(uint32_t k0, uint32_t k1, uint32_t idx) {
  uint32_t a, b;
  tf2x32(k0, k1, 0u, idx, &a, &b);
  uint32_t bits = a ^ b;
  return __uint_as_float((bits >> 9) | 0x3f800000u) - 1.0f;
}

// ---------------- monotone float<->uint for atomic min/max ----------------
__device__ __forceinline__ unsigned fmono(float x) {
  unsigned u = __float_as_uint(x);
  return (u >> 31) ? ~u : (u | 0x80000000u);
}
__device__ __forceinline__ float funmono(unsigned m) {
  return __uint_as_float((m >> 31) ? (m ^ 0x80000000u) : ~m);
}

__device__ __forceinline__ void push_minmax(unsigned* slots, unsigned cm, unsigned cM) {
  volatile unsigned* vs = (volatile unsigned*)slots;
  if (cm < vs[0]) atomicMin(&slots[0], cm);
  if (cM > vs[1]) atomicMax(&slots[1], cM);
}

// bf16 truncation — exact for integer values <= 256 (our only use)
__device__ __forceinline__ unsigned short f2bf(float x) {
  return (unsigned short)(__float_as_uint(x) >> 16);
}

// fp16 hi/lo split: x ~= hi + lo with residual <= 2^-23 |x|
__device__ __forceinline__ void f16split(float x, unsigned short* h, unsigned short* l) {
  _Float16 hf = (_Float16)x;
  float r = x - (float)hf;         // exact (Sterbenz)
  _Float16 lf = (_Float16)r;
  *h = __builtin_bit_cast(unsigned short, hf);
  *l = __builtin_bit_cast(unsigned short, lf);
}

__device__ __forceinline__ float fq_st_i(float x, float lo, float hi, float scale,
                                         float scinv, float u) {
  float c = fminf(fmaxf(x, lo), hi);
  float t = (c - lo) * scinv;
  return floorf(t + u) * scale + lo;
}

// ---------------- tiny kernels ----------------
__global__ void init_ws(unsigned* su) {
  int t = threadIdx.x;
  if (t < 12) su[t] = (t & 1) ? 0u : 0xFFFFFFFFu;
}

// cw stat block stride 8: [lo, hi, scale, lut_thr, inv_scale, _, _, _]
__global__ void finalize_kernel(const unsigned* __restrict__ slots,
                                const float* __restrict__ oldmm,
                                float* __restrict__ outc) {
  if (threadIdx.x == 0) {
    float clo = funmono(slots[0]), chi = funmono(slots[1]);
    float o0 = oldmm[0], o1 = oldmm[1];
    bool fin = isfinite(o0) && isfinite(o1);
    float lo = fin ? (0.9f * o0 + 0.1f * clo) : clo;
    float hi = fin ? (0.9f * o1 + 0.1f * chi) : chi;
    float sc = (hi - lo) / 255.0f;
    outc[0] = lo;
    outc[1] = hi;
    outc[2] = sc;
    outc[3] = 0.02004f * fmaxf(fabsf(lo), fabsf(hi));
    outc[4] = 1.0f / sc;
  }
}

__global__ __launch_bounds__(256) void minmax_kernel(const float4* __restrict__ x,
                                                     int n4, unsigned* __restrict__ slots) {
  float lmin = INFINITY, lmax = -INFINITY;
  for (int i = blockIdx.x * blockDim.x + threadIdx.x; i < n4; i += gridDim.x * blockDim.x) {
    float4 a = x[i];
    lmin = fminf(lmin, fminf(fminf(a.x, a.y), fminf(a.z, a.w)));
    lmax = fmaxf(lmax, fmaxf(fmaxf(a.x, a.y), fmaxf(a.z, a.w)));
  }
  __shared__ unsigned bmin, bmax;
  if (threadIdx.x == 0) { bmin = 0xFFFFFFFFu; bmax = 0u; }
  __syncthreads();
  atomicMin(&bmin, fmono(lmin));
  atomicMax(&bmax, fmono(lmax));
  __syncthreads();
  if (threadIdx.x == 0) push_minmax(slots, bmin, bmax);
}

// ---------------- quantization + split prepasses ----------------
// Q: n = round((clip(q)-lo)/sc) in [0,255] as bf16; plus fp16 hi/lo split of raw q
__global__ __launch_bounds__(256) void quant_q_kernel(const float* __restrict__ q,
    unsigned short* __restrict__ qnb, unsigned short* __restrict__ qh,
    unsigned short* __restrict__ ql, const float* __restrict__ cw) {
  const float lo = cw[0], hi = cw[1], sc = cw[2];
  int idx = blockIdx.x * 256 + threadIdx.x;
  float4 x = ((const float4*)q)[idx];
  float xa[4] = {x.x, x.y, x.z, x.w};
  ushort4 o, oh, ol;
  unsigned short* op = (unsigned short*)&o;
  unsigned short* ohp = (unsigned short*)&oh;
  unsigned short* olp = (unsigned short*)&ol;
#pragma unroll
  for (int j = 0; j < 4; ++j) {
    float n = rintf((fminf(fmaxf(xa[j], lo), hi) - lo) / sc);
    op[j] = f2bf(n);
    f16split(xa[j], &ohp[j], &olp[j]);
  }
  ((ushort4*)qnb)[idx] = o;
  ((ushort4*)qh)[idx] = oh;
  ((ushort4*)ql)[idx] = ol;
}

// K: z/m' bf16 + per-row sums Z,M + fp16 hi/lo split of raw k
__global__ __launch_bounds__(256) void quant_k_kernel(const float* __restrict__ k,
    unsigned short* __restrict__ kzb, unsigned short* __restrict__ kmb,
    unsigned short* __restrict__ kh, unsigned short* __restrict__ kl,
    float* __restrict__ Zk, float* __restrict__ Mk, const float* __restrict__ cw) {
  const float lo = cw[8], hi = cw[9], sc = cw[10], thr = cw[11];
  const int tid = threadIdx.x;
  const int row = blockIdx.x * 8 + (tid >> 5);      // global key row [0, 8*2048)
  const int c4 = (tid & 31) * 4;
  float4 x = *(const float4*)&k[(size_t)row * HD + c4];
  float xa[4] = {x.x, x.y, x.z, x.w};
  ushort4 zo, mo, ho, lo_;
  unsigned short* zp = (unsigned short*)&zo;
  unsigned short* mp = (unsigned short*)&mo;
  unsigned short* hp = (unsigned short*)&ho;
  unsigned short* lp = (unsigned short*)&lo_;
  float zs = 0.f, ms = 0.f;
#pragma unroll
  for (int j = 0; j < 4; ++j) {
    float m = rintf((fminf(fmaxf(xa[j], lo), hi) - lo) / sc);
    float kq = m * sc + lo;
    float z = (fabsf(kq) < thr) ? 0.f : 1.f;
    float mq = z * m;
    zs += z; ms += mq;
    zp[j] = f2bf(z); mp[j] = f2bf(mq);
    f16split(xa[j], &hp[j], &lp[j]);
  }
  *(ushort4*)&kzb[(size_t)row * HD + c4] = zo;
  *(ushort4*)&kmb[(size_t)row * HD + c4] = mo;
  *(ushort4*)&kh[(size_t)row * HD + c4] = ho;
  *(ushort4*)&kl[(size_t)row * HD + c4] = lo_;
#pragma unroll
  for (int off = 16; off > 0; off >>= 1) {
    zs += __shfl_xor(zs, off);
    ms += __shfl_xor(ms, off);
  }
  if ((tid & 31) == 0) { Zk[row] = zs; Mk[row] = ms; }
}

// V: transposed z/m' (bf16) + transposed fp16 hi/lo of raw v: [kvh][d][kp]
__global__ __launch_bounds__(256) void quant_v_kernel(const float* __restrict__ v,
    unsigned short* __restrict__ vzT, unsigned short* __restrict__ vmT,
    unsigned short* __restrict__ vhT, unsigned short* __restrict__ vlT,
    const float* __restrict__ cw) {
  const float lo = cw[16], hi = cw[17], sc = cw[18], thr = cw[19];
  const int kvh = blockIdx.y, dg = blockIdx.x;   // dg: 0..31 (4 d's each)
  const int tid = threadIdx.x;
  for (int ch = 0; ch < 8; ++ch) {
    int kp = ch * 256 + tid;
    float4 x = *(const float4*)&v[((size_t)(kvh * SEQ + kp)) * HD + dg * 4];
    float xa[4] = {x.x, x.y, x.z, x.w};
#pragma unroll
    for (int j = 0; j < 4; ++j) {
      float m = rintf((fminf(fmaxf(xa[j], lo), hi) - lo) / sc);
      float vq = m * sc + lo;
      float z = (fabsf(vq) < thr) ? 0.f : 1.f;
      float mq = z * m;
      size_t o = ((size_t)(kvh * HD + dg * 4 + j)) * SEQ + kp;
      vzT[o] = f2bf(z);
      vmT[o] = f2bf(mq);
      unsigned short hb, lb;
      f16split(xa[j], &hb, &lb);
      vhT[o] = hb;
      vlT[o] = lb;
    }
  }
}

// ---------------- QK raw min/max via 3-term fp16-split MFMA ----------------
// acc = Ah*Bh + Ah*Bl + Al*Bh  (~fp32 accurate); full S x S coverage
__global__ __launch_bounds__(256, 2) void qk_raw_mfma(
    const unsigned short* __restrict__ qh, const unsigned short* __restrict__ ql,
    const unsigned short* __restrict__ kh, const unsigned short* __restrict__ kl,
    unsigned* __restrict__ slots) {
  const int kbi = blockIdx.x, qbi = blockIdx.y, h = blockIdx.z;
  const int kvh = h >> 2;
  const int tid = threadIdx.x;
  const int wid = tid >> 6, lane = tid & 63;
  const int fr = lane & 15, fg = lane >> 4;
  const int qrow0 = qbi * 128 + wid * 32;
  const int kcol0 = kbi * 128;
  const unsigned short* qhg = qh + (size_t)h * SEQ * HD;
  const unsigned short* qlg = ql + (size_t)h * SEQ * HD;
  const unsigned short* khg = kh + (size_t)kvh * SEQ * HD;
  const unsigned short* klg = kl + (size_t)kvh * SEQ * HD;
  f32x4 acc[2][8];
  const f32x4 z4 = {0.f, 0.f, 0.f, 0.f};
#pragma unroll
  for (int rg = 0; rg < 2; ++rg)
#pragma unroll
    for (int cg = 0; cg < 8; ++cg) acc[rg][cg] = z4;

#pragma unroll
  for (int ks = 0; ks < 4; ++ks) {
    const int d0 = ks * 32 + fg * 8;
    const f16x8 a0h = *(const f16x8*)&qhg[(size_t)(qrow0 + fr) * HD + d0];
    const f16x8 a0l = *(const f16x8*)&qlg[(size_t)(qrow0 + fr) * HD + d0];
    const f16x8 a1h = *(const f16x8*)&qhg[(size_t)(qrow0 + 16 + fr) * HD + d0];
    const f16x8 a1l = *(const f16x8*)&qlg[(size_t)(qrow0 + 16 + fr) * HD + d0];
#pragma unroll
    for (int cg = 0; cg < 8; ++cg) {
      const size_t boff = (size_t)(kcol0 + cg * 16 + fr) * HD + d0;
      const f16x8 bh = *(const f16x8*)&khg[boff];
      const f16x8 bl = *(const f16x8*)&klg[boff];
      acc[0][cg] = __builtin_amdgcn_mfma_f32_16x16x32_f16(a0h, bh, acc[0][cg], 0, 0, 0);
      acc[0][cg] = __builtin_amdgcn_mfma_f32_16x16x32_f16(a0h, bl, acc[0][cg], 0, 0, 0);
      acc[0][cg] = __builtin_amdgcn_mfma_f32_16x16x32_f16(a0l, bh, acc[0][cg], 0, 0, 0);
      acc[1][cg] = __builtin_amdgcn_mfma_f32_16x16x32_f16(a1h, bh, acc[1][cg], 0, 0, 0);
      acc[1][cg] = __builtin_amdgcn_mfma_f32_16x16x32_f16(a1h, bl, acc[1][cg], 0, 0, 0);
      acc[1][cg] = __builtin_amdgcn_mfma_f32_16x16x32_f16(a1l, bh, acc[1][cg], 0, 0, 0);
    }
  }
  float lmin = INFINITY, lmax = -INFINITY;
#pragma unroll
  for (int rg = 0; rg < 2; ++rg)
#pragma unroll
    for (int cg = 0; cg < 8; ++cg)
#pragma unroll
      for (int r = 0; r < 4; ++r) {
        const float rv = acc[rg][cg][r] * SCALING_F;
        lmin = fminf(lmin, rv);
        lmax = fmaxf(lmax, rv);
      }
  __shared__ unsigned bmin, bmax;
  if (tid == 0) { bmin = 0xFFFFFFFFu; bmax = 0u; }
  __syncthreads();
  atomicMin(&bmin, fmono(lmin));
  atomicMax(&bmax, fmono(lmax));
  __syncthreads();
  if (tid == 0) push_minmax(slots, bmin, bmax);
}

// ---------------- QK quant (bf16 MFMA, exact integer grid) ----------------
__global__ __launch_bounds__(256, 2) void qk_quant_kernel(
    const unsigned short* __restrict__ qnb, const unsigned short* __restrict__ kzb,
    const unsigned short* __restrict__ kmb, const float* __restrict__ Zk,
    const float* __restrict__ Mk, float* __restrict__ qdot,
    const float* __restrict__ cw) {
  const int kbi = blockIdx.x, qbi = blockIdx.y, h = blockIdx.z;
  if (kbi > qbi) return;            // raw-only region above the diagonal
  const int kvh = h >> 2;
  const float qlo = cw[0], qsc = cw[2];
  const float klo = cw[8], ksc = cw[10];
  const int tid = threadIdx.x;
  const int wid = tid >> 6, lane = tid & 63;
  const int fr = lane & 15, fg = lane >> 4;
  const int qrow0 = qbi * 128 + wid * 32;
  const int kcol0 = kbi * 128;
  const unsigned short* qg = qnb + (size_t)h * SEQ * HD;
  const unsigned short* zg = kzb + (size_t)kvh * SEQ * HD;
  const unsigned short* mg = kmb + (size_t)kvh * SEQ * HD;
  f32x4 P[2][8], R[2][8];
  const f32x4 z4 = {0.f, 0.f, 0.f, 0.f};
#pragma unroll
  for (int rg = 0; rg < 2; ++rg)
#pragma unroll
    for (int cg = 0; cg < 8; ++cg) { P[rg][cg] = z4; R[rg][cg] = z4; }

#pragma unroll
  for (int ks = 0; ks < 4; ++ks) {
    const int d0 = ks * 32 + fg * 8;
    const bf16x8 a0 = *(const bf16x8*)&qg[(size_t)(qrow0 + fr) * HD + d0];
    const bf16x8 a1 = *(const bf16x8*)&qg[(size_t)(qrow0 + 16 + fr) * HD + d0];
#pragma unroll
    for (int cg = 0; cg < 8; ++cg) {
      const size_t boff = (size_t)(kcol0 + cg * 16 + fr) * HD + d0;
      const bf16x8 bz = *(const bf16x8*)&zg[boff];
      const bf16x8 bm = *(const bf16x8*)&mg[boff];
      P[0][cg] = __builtin_amdgcn_mfma_f32_16x16x32_bf16(a0, bz, P[0][cg], 0, 0, 0);
      P[1][cg] = __builtin_amdgcn_mfma_f32_16x16x32_bf16(a1, bz, P[1][cg], 0, 0, 0);
      R[0][cg] = __builtin_amdgcn_mfma_f32_16x16x32_bf16(a0, bm, R[0][cg], 0, 0, 0);
      R[1][cg] = __builtin_amdgcn_mfma_f32_16x16x32_bf16(a1, bm, R[1][cg], 0, 0, 0);
    }
  }
#pragma unroll
  for (int cg = 0; cg < 8; ++cg) {
    const int col = kcol0 + cg * 16 + fr;
    const float Z = Zk[kvh * SEQ + col], M = Mk[kvh * SEQ + col];
    const float base = qlo * (klo * Z + ksc * M);
#pragma unroll
    for (int rg = 0; rg < 2; ++rg)
#pragma unroll
      for (int r = 0; r < 4; ++r) {
        const int row = qrow0 + rg * 16 + fg * 4 + r;
        qdot[((size_t)h * SEQ + row) * SEQ + col] =
            base + qsc * (klo * P[rg][cg][r] + ksc * R[rg][cg][r]);
      }
  }
}

// ---------------- softmax: causal skip + stoch-quant + softmax ----------------
__global__ __launch_bounds__(256) void softmax_kernel(
    float* __restrict__ attn, const float* __restrict__ cw,
    unsigned* __restrict__ slots, uint32_t uk0, uint32_t uk1) {
  const int row = blockIdx.x;          // h*SEQ + qi
  const int qi = row & (SEQ - 1);
  const int tid = threadIdx.x;
  const float lo = cw[24], hi = cw[25], sc = cw[26], sci = cw[28];
  float* prow = attn + (size_t)row * SEQ;
  const uint32_t jbase = (uint32_t)row << 11;

  float vals[8];
  float lmax = -INFINITY;
#pragma unroll
  for (int m = 0; m < 2; ++m) {
    int ki = m * 1024 + tid * 4;
    if (ki <= qi) {
      float4 x4 = *(const float4*)&prow[ki];
      float xa[4] = {x4.x, x4.y, x4.z, x4.w};
#pragma unroll
      for (int j = 0; j < 4; ++j) {
        if (ki + j <= qi) {
          float u = tf_uniform(uk0, uk1, jbase + (uint32_t)(ki + j));
          float lg = fq_st_i(xa[j], lo, hi, sc, sci, u) * SCALING_F;
          vals[m * 4 + j] = lg;
          lmax = fmaxf(lmax, lg);
        } else {
          vals[m * 4 + j] = -INFINITY;
        }
      }
    } else {
      vals[m * 4 + 0] = vals[m * 4 + 1] = vals[m * 4 + 2] = vals[m * 4 + 3] = -INFINITY;
    }
  }

  __shared__ float smax[4], ssum[4], smn[4], smx[4];
#pragma unroll
  for (int off = 32; off > 0; off >>= 1) lmax = fmaxf(lmax, __shfl_xor(lmax, off));
  if ((tid & 63) == 0) smax[tid >> 6] = lmax;
  __syncthreads();
  float rmax = fmaxf(fmaxf(smax[0], smax[1]), fmaxf(smax[2], smax[3]));

  float lsum = 0.f;
#pragma unroll
  for (int e = 0; e < 8; ++e) { vals[e] = __expf(vals[e] - rmax); lsum += vals[e]; }
#pragma unroll
  for (int off = 32; off > 0; off >>= 1) lsum += __shfl_xor(lsum, off);
  if ((tid & 63) == 0) ssum[tid >> 6] = lsum;
  __syncthreads();
  float rinv = 1.0f / (ssum[0] + ssum[1] + ssum[2] + ssum[3]);

  float lmin2 = INFINITY, lmax2 = -INFINITY;
#pragma unroll
  for (int m = 0; m < 2; ++m) {
    int ki = m * 1024 + tid * 4;
    float4 st;
    float* stp = (float*)&st;
#pragma unroll
    for (int j = 0; j < 4; ++j) {
      float w = vals[m * 4 + j] * rinv;
      stp[j] = w;
      lmin2 = fminf(lmin2, w);
      lmax2 = fmaxf(lmax2, w);
    }
    *(float4*)&prow[ki] = st;
  }
#pragma unroll
  for (int off = 32; off > 0; off >>= 1) {
    lmin2 = fminf(lmin2, __shfl_xor(lmin2, off));
    lmax2 = fmaxf(lmax2, __shfl_xor(lmax2, off));
  }
  if ((tid & 63) == 0) { smn[tid >> 6] = lmin2; smx[tid >> 6] = lmax2; }
  __syncthreads();
  if (tid == 0) {
    float mn = fminf(fminf(smn[0], smn[1]), fminf(smn[2], smn[3]));
    float mx = fmaxf(fmaxf(smx[0], smx[1]), fmaxf(smx[2], smx[3]));
    push_minmax(slots, fmono(mn), fmono(mx));
  }
}

// ---------------- AV raw min/max via 3-term fp16-split MFMA ----------------
// A: attn fp32 split on the fly; B: vhT/vlT prepass. Causal chunk limit.
__device__ __forceinline__ void pack_split8(const float* __restrict__ p,
                                            f16x8* ah, f16x8* al) {
  float4 w0 = *(const float4*)p;
  float4 w1 = *(const float4*)(p + 4);
  float wa[8] = {w0.x, w0.y, w0.z, w0.w, w1.x, w1.y, w1.z, w1.w};
  f16x8 h, l;
#pragma unroll
  for (int j = 0; j < 8; ++j) {
    _Float16 hf = (_Float16)wa[j];
    h[j] = hf;
    l[j] = (_Float16)(wa[j] - (float)hf);
  }
  *ah = h; *al = l;
}

__global__ __launch_bounds__(256, 2) void av_raw_mfma(
    const float* __restrict__ attn, const unsigned short* __restrict__ vhT,
    const unsigned short* __restrict__ vlT, unsigned* __restrict__ slots) {
  const int qbi = (int)gridDim.x - 1 - (int)blockIdx.x;  // largest blocks first
  const int h = blockIdx.y, kvh = h >> 2;
  const int tid = threadIdx.x;
  const int wid = tid >> 6, lane = tid & 63;
  const int fr = lane & 15, fg = lane >> 4;
  const int qrow0 = qbi * 128 + wid * 32;
  const float* ag = attn + (size_t)h * SEQ * SEQ;
  const unsigned short* bhg = vhT + (size_t)kvh * HD * SEQ;
  const unsigned short* blg = vlT + (size_t)kvh * HD * SEQ;
  const int nk = 4 * (qbi + 1);   // attn cols beyond (qbi+1)*128 are exactly 0
  f32x4 acc[2][8];
  const f32x4 z4 = {0.f, 0.f, 0.f, 0.f};
#pragma unroll
  for (int rg = 0; rg < 2; ++rg)
#pragma unroll
    for (int cg = 0; cg < 8; ++cg) acc[rg][cg] = z4;

  for (int ks = 0; ks < nk; ++ks) {
    const int kp0 = ks * 32 + fg * 8;
    f16x8 a0h, a0l, a1h, a1l;
    pack_split8(ag + (size_t)(qrow0 + fr) * SEQ + kp0, &a0h, &a0l);
    pack_split8(ag + (size_t)(qrow0 + 16 + fr) * SEQ + kp0, &a1h, &a1l);
#pragma unroll
    for (int cg = 0; cg < 8; ++cg) {
      const size_t boff = (size_t)(cg * 16 + fr) * SEQ + kp0;
      const f16x8 bh = *(const f16x8*)&bhg[boff];
      const f16x8 bl = *(const f16x8*)&blg[boff];
      acc[0][cg] = __builtin_amdgcn_mfma_f32_16x16x32_f16(a0h, bh, acc[0][cg], 0, 0, 0);
      acc[0][cg] = __builtin_amdgcn_mfma_f32_16x16x32_f16(a0h, bl, acc[0][cg], 0, 0, 0);
      acc[0][cg] = __builtin_amdgcn_mfma_f32_16x16x32_f16(a0l, bh, acc[0][cg], 0, 0, 0);
      acc[1][cg] = __builtin_amdgcn_mfma_f32_16x16x32_f16(a1h, bh, acc[1][cg], 0, 0, 0);
      acc[1][cg] = __builtin_amdgcn_mfma_f32_16x16x32_f16(a1h, bl, acc[1][cg], 0, 0, 0);
      acc[1][cg] = __builtin_amdgcn_mfma_f32_16x16x32_f16(a1l, bh, acc[1][cg], 0, 0, 0);
    }
  }
  float lmin = INFINITY, lmax = -INFINITY;
#pragma unroll
  for (int rg = 0; rg < 2; ++rg)
#pragma unroll
    for (int cg = 0; cg < 8; ++cg)
#pragma unroll
      for (int r = 0; r < 4; ++r) {
        lmin = fminf(lmin, acc[rg][cg][r]);
        lmax = fmaxf(lmax, acc[rg][cg][r]);
      }
  __shared__ unsigned bmin, bmax;
  if (tid == 0) { bmin = 0xFFFFFFFFu; bmax = 0u; }
  __syncthreads();
  atomicMin(&bmin, fmono(lmin));
  atomicMax(&bmax, fmono(lmax));
  __syncthreads();
  if (tid == 0) push_minmax(slots, bmin, bmax);
}

// ---------------- AV quant (bf16 MFMA): out = asc*(vlo*P + vsc*R) ----------------
__device__ __forceinline__ bf16x8 pack_a8(const float* __restrict__ ar,
                                          float lo, float hi, float sc) {
  float4 w0 = *(const float4*)ar;
  float4 w1 = *(const float4*)(ar + 4);
  float wa[8] = {w0.x, w0.y, w0.z, w0.w, w1.x, w1.y, w1.z, w1.w};
  bf16x8 r;
#pragma unroll
  for (int j = 0; j < 8; ++j) {
    float n = rintf((fminf(fmaxf(wa[j], lo), hi) - lo) / sc);
    r[j] = (short)(__float_as_uint(n) >> 16);
  }
  return r;
}

__global__ __launch_bounds__(256, 2) void av_quant_kernel(
    const float* __restrict__ attn, const unsigned short* __restrict__ vzT,
    const unsigned short* __restrict__ vmT, float* __restrict__ out0,
    const float* __restrict__ cw) {
  const int qbi = (int)gridDim.x - 1 - (int)blockIdx.x;
  const int h = blockIdx.y, kvh = h >> 2;
  const float alo = cw[32], ahi = cw[33], asc = cw[34];
  const float vlo = cw[16], vsc = cw[18];
  const int tid = threadIdx.x;
  const int wid = tid >> 6, lane = tid & 63;
  const int fr = lane & 15, fg = lane >> 4;
  const int qrow0 = qbi * 128 + wid * 32;
  const float* ag = attn + (size_t)h * SEQ * SEQ;
  const unsigned short* zg = vzT + (size_t)kvh * HD * SEQ;
  const unsigned short* mg = vmT + (size_t)kvh * HD * SEQ;
  const int nk = 4 * (qbi + 1);
  f32x4 P[2][8], R[2][8];
  const f32x4 z4 = {0.f, 0.f, 0.f, 0.f};
#pragma unroll
  for (int rg = 0; rg < 2; ++rg)
#pragma unroll
    for (int cg = 0; cg < 8; ++cg) { P[rg][cg] = z4; R[rg][cg] = z4; }

  for (int ks = 0; ks < nk; ++ks) {
    const int kp0 = ks * 32 + fg * 8;
    const bf16x8 a0 = pack_a8(ag + (size_t)(qrow0 + fr) * SEQ + kp0, alo, ahi, asc);
    const bf16x8 a1 = pack_a8(ag + (size_t)(qrow0 + 16 + fr) * SEQ + kp0, alo, ahi, asc);
#pragma unroll
    for (int cg = 0; cg < 8; ++cg) {
      const size_t boff = (size_t)(cg * 16 + fr) * SEQ + kp0;
      const bf16x8 bz = *(const bf16x8*)&zg[boff];
      const bf16x8 bm = *(const bf16x8*)&mg[boff];
      P[0][cg] = __builtin_amdgcn_mfma_f32_16x16x32_bf16(a0, bz, P[0][cg], 0, 0, 0);
      P[1][cg] = __builtin_amdgcn_mfma_f32_16x16x32_bf16(a1, bz, P[1][cg], 0, 0, 0);
      R[0][cg] = __builtin_amdgcn_mfma_f32_16x16x32_bf16(a0, bm, R[0][cg], 0, 0, 0);
      R[1][cg] = __builtin_amdgcn_mfma_f32_16x16x32_bf16(a1, bm, R[1][cg], 0, 0, 0);
    }
  }
#pragma unroll
  for (int cg = 0; cg < 8; ++cg) {
    const int dcol = cg * 16 + fr;
#pragma unroll
    for (int rg = 0; rg < 2; ++rg)
#pragma unroll
      for (int r = 0; r < 4; ++r) {
        const int row = qrow0 + rg * 16 + fg * 4 + r;
        out0[((size_t)row * NH + h) * HD + dcol] =
            asc * (vlo * P[rg][cg][r] + vsc * R[rg][cg][r]);
      }
  }
}

// ---------------- final elementwise stochastic quantization of out0 ----------------
__global__ __launch_bounds__(256) void stoch_kernel(float* __restrict__ out0,
                                                    const float* __restrict__ cw,
                                                    uint32_t uk0, uint32_t uk1) {
  int idx = blockIdx.x * 256 + threadIdx.x;
  const float lo = cw[40], hi = cw[41], sc = cw[42], sci = cw[44];
  int qi = idx >> 12;                 // / (NH*HD)
  int rem = idx & 4095;
  int h = rem >> 7, d = rem & 127;
  uint32_t j = ((uint32_t)h * SEQ + (uint32_t)qi) * HD + (uint32_t)d;  // BHSD flat
  float x = out0[idx];
  float u = tf_uniform(uk0, uk1, j);
  out0[idx] = fq_st_i(x, lo, hi, sc, sci, u);
}

// ---------------- launcher ----------------
extern "C" void kernel_launch(void* const* d_in, const int* in_sizes, int n_in,
                              void* d_out, int out_size, void* d_ws, size_t ws_size,
                              hipStream_t stream) {
  (void)in_sizes; (void)n_in; (void)out_size; (void)ws_size;
  const float* q      = (const float*)d_in[0];
  const float* k      = (const float*)d_in[1];
  const float* v      = (const float*)d_in[2];
  const float* q_old  = (const float*)d_in[4];
  const float* k_old  = (const float*)d_in[5];
  const float* qk_old = (const float*)d_in[6];
  const float* a_old  = (const float*)d_in[7];
  const float* v_old  = (const float*)d_in[8];
  const float* av_old = (const float*)d_in[9];
  float* out0 = (float*)d_out;
  float* out1 = out0 + (size_t)OUT0_N;
  unsigned* su = (unsigned*)d_ws;
  float* cw = (float*)d_ws + 16;

  // d_ws scratch: vzT/vmT (live until av_quant), Zk/Mk  (~8.5 MB)
  unsigned short* vzT = (unsigned short*)((char*)d_ws + 1024);
  unsigned short* vmT = vzT + (size_t)NKVH * SEQ * HD;
  float* Zk = (float*)(vmT + (size_t)NKVH * SEQ * HD);
  float* Mk = Zk + NKVH * SEQ;

  // out0-region scratch (exactly fills 32 MB; all consumed before av_quant
  // overwrites out0): qnb(16MB) kzb(4MB) kmb(4MB) vhT(4MB) vlT(4MB)
  unsigned short* qnb = (unsigned short*)out0;
  unsigned short* kzb = qnb + (size_t)NH * SEQ * HD;
  unsigned short* kmb = kzb + (size_t)NKVH * SEQ * HD;
  unsigned short* vhT = kmb + (size_t)NKVH * SEQ * HD;
  unsigned short* vlT = vhT + (size_t)NKVH * SEQ * HD;

  // out1-region scratch (consumed by qk_raw_mfma BEFORE qk_quant writes out1;
  // in-order stream guarantees ordering): qh/ql (16MB ea), kh/kl (4MB ea)
  unsigned short* qh = (unsigned short*)out1;
  unsigned short* ql = qh + (size_t)NH * SEQ * HD;
  unsigned short* kh = ql + (size_t)NH * SEQ * HD;
  unsigned short* kl = kh + (size_t)NKVH * SEQ * HD;

  uint32_t kq0, kq1, ka0, ka1;
  tf2x32(0u, 0u, 0u, 0u, &kq0, &kq1);
  tf2x32(0u, 0u, 0u, 1u, &ka0, &ka1);

  init_ws<<<1, 32, 0, stream>>>(su);
  minmax_kernel<<<1024, 256, 0, stream>>>((const float4*)q, (NH * SEQ * HD) / 4, su + 0);
  minmax_kernel<<<512, 256, 0, stream>>>((const float4*)k, (NKVH * SEQ * HD) / 4, su + 2);
  minmax_kernel<<<512, 256, 0, stream>>>((const float4*)v, (NKVH * SEQ * HD) / 4, su + 4);
  finalize_kernel<<<1, 1, 0, stream>>>(su + 0, q_old, cw + 0);
  finalize_kernel<<<1, 1, 0, stream>>>(su + 2, k_old, cw + 8);
  finalize_kernel<<<1, 1, 0, stream>>>(su + 4, v_old, cw + 16);

  quant_q_kernel<<<(NH * SEQ * HD) / 4 / 256, 256, 0, stream>>>(q, qnb, qh, ql, cw);
  quant_k_kernel<<<(NKVH * SEQ) / 8, 256, 0, stream>>>(k, kzb, kmb, kh, kl, Zk, Mk, cw);
  quant_v_kernel<<<dim3(32, NKVH), 256, 0, stream>>>(v, vzT, vmT, vhT, vlT, cw);

  qk_raw_mfma<<<dim3(16, 16, NH), 256, 0, stream>>>(qh, ql, kh, kl, su + 6);
  finalize_kernel<<<1, 1, 0, stream>>>(su + 6, qk_old, cw + 24);
  qk_quant_kernel<<<dim3(16, 16, NH), 256, 0, stream>>>(qnb, kzb, kmb, Zk, Mk, out1, cw);

  softmax_kernel<<<NH * SEQ, 256, 0, stream>>>(out1, cw, su + 8, kq0, kq1);
  finalize_kernel<<<1, 1, 0, stream>>>(su + 8, a_old, cw + 32);

  av_raw_mfma<<<dim3(16, NH), 256, 0, stream>>>(out1, vhT, vlT, su + 10);
  finalize_kernel<<<1, 1, 0, stream>>>(su + 10, av_old, cw + 40);
  av_quant_kernel<<<dim3(16, NH), 256, 0, stream>>>(out1, vzT, vmT, out0, cw);

  stoch_kernel<<<OUT0_N / 256, 256, 0, stream>>>(out0, cw, ka0, ka1);
}

// Round 3
// 1566.426 us; speedup vs baseline: 1.6912x; 1.4009x over previous
//
#include <hip/hip_runtime.h>
#include <stdint.h>
#include <math.h>

#pragma clang fp contract(off)

#define NH 32
#define NKVH 8
#define SEQ 2048
#define HD 128
#define SCALING_F 0.08838834764831845f
#define OUT0_N (SEQ*NH*HD)   /* 8388608 */

typedef __attribute__((ext_vector_type(8))) short bf16x8;      // 8 bf16 = 4 VGPRs
typedef __attribute__((ext_vector_type(8))) _Float16 f16x8;    // 8 f16  = 4 VGPRs
typedef __attribute__((ext_vector_type(8))) unsigned short u16x8;
typedef __attribute__((ext_vector_type(4))) float f32x4;

// ---------------- threefry2x32 (JAX-compatible) ----------------
__host__ __device__ __forceinline__ void tf2x32(uint32_t k0, uint32_t k1,
    uint32_t x0, uint32_t x1, uint32_t* o0, uint32_t* o1) {
  uint32_t k2 = k0 ^ k1 ^ 0x1BD11BDAu;
  x0 += k0; x1 += k1;
#define TFR(r) { x0 += x1; x1 = (x1 << (r)) | (x1 >> (32 - (r))); x1 ^= x0; }
  TFR(13) TFR(15) TFR(26) TFR(6)
  x0 += k1; x1 += k2 + 1u;
  TFR(17) TFR(29) TFR(16) TFR(24)
  x0 += k2; x1 += k0 + 2u;
  TFR(13) TFR(15) TFR(26) TFR(6)
  x0 += k0; x1 += k1 + 3u;
  TFR(17) TFR(29) TFR(16) TFR(24)
  x0 += k1; x1 += k2 + 4u;
  TFR(13) TFR(15) TFR(26) TFR(6)
  x0 += k2; x1 += k0 + 5u;
#undef TFR
  *o0 = x0; *o1 = x1;
}

__device__ __forceinline__ float tf_uniform(uint32_t k0, uint32_t k1, uint32_t idx) {
  uint32_t a, b;
  tf2x32(k0, k1, 0u, idx, &a, &b);
  uint32_t bits = a ^ b;
  return __uint_as_float((bits >> 9) | 0x3f800000u) - 1.0f;
}

// ---------------- monotone float<->uint for atomic min/max ----------------
__device__ __forceinline__ unsigned fmono(float x) {
  unsigned u = __float_as_uint(x);
  return (u >> 31) ? ~u : (u | 0x80000000u);
}
__device__ __forceinline__ float funmono(unsigned m) {
  return __uint_as_float((m >> 31) ? (m ^ 0x80000000u) : ~m);
}

__device__ __forceinline__ void push_minmax(unsigned* slots, unsigned cm, unsigned cM) {
  volatile unsigned* vs = (volatile unsigned*)slots;
  if (cm < vs[0]) atomicMin(&slots[0], cm);
  if (cM > vs[1]) atomicMax(&slots[1], cM);
}

// bf16 truncation — exact for integer values <= 256 (our only use)
__device__ __forceinline__ unsigned short f2bf(float x) {
  return (unsigned short)(__float_as_uint(x) >> 16);
}

// fp16 hi/lo split: x ~= hi + lo with residual <= 2^-23 |x|
__device__ __forceinline__ void f16split(float x, unsigned short* h, unsigned short* l) {
  _Float16 hf = (_Float16)x;
  float r = x - (float)hf;         // exact (Sterbenz)
  _Float16 lf = (_Float16)r;
  *h = __builtin_bit_cast(unsigned short, hf);
  *l = __builtin_bit_cast(unsigned short, lf);
}

__device__ __forceinline__ float fq_st_i(float x, float lo, float hi, float scale,
                                         float scinv, float u) {
  float c = fminf(fmaxf(x, lo), hi);
  float t = (c - lo) * scinv;
  return floorf(t + u) * scale + lo;
}

// ---------------- swizzled LDS panel helpers ----------------
// Panel = [128 rows][128 2B-elements], row stride 256B in LDS.
// Byte offset swizzle: ^ ((row&7)<<4). Read pattern (16 fr-lanes, fixed c16)
// would be a 16-way slot conflict unswizzled; swizzled -> (c16^fr)&7 spreads
// each quarter-wave over all 8 slots (conflict-free minimum).
#define SWZ_OFF(row, c16) ((((row) * 256) + ((c16) * 16)) ^ (((row) & 7) << 4))

__device__ __forceinline__ void stage_panel(const unsigned short* __restrict__ g,
                                            int rowstride, unsigned short* s, int tid) {
#pragma unroll
  for (int it = 0; it < 8; ++it) {
    const int i = it * 256 + tid;
    const int row = i >> 4, c16 = i & 15;
    const u16x8 val = *(const u16x8*)&g[(size_t)row * rowstride + c16 * 8];
    *(u16x8*)((char*)s + SWZ_OFF(row, c16)) = val;
  }
}

__device__ __forceinline__ f16x8 frag_h(const unsigned short* s, int row, int c16) {
  return *(const f16x8*)((const char*)s + SWZ_OFF(row, c16));
}
__device__ __forceinline__ bf16x8 frag_b(const unsigned short* s, int row, int c16) {
  return *(const bf16x8*)((const char*)s + SWZ_OFF(row, c16));
}

// ---------------- tiny kernels ----------------
__global__ void init_ws(unsigned* su) {
  int t = threadIdx.x;
  if (t < 12) su[t] = (t & 1) ? 0u : 0xFFFFFFFFu;
}

// cw stat block stride 8: [lo, hi, scale, lut_thr, inv_scale, _, _, _]
__global__ void finalize_kernel(const unsigned* __restrict__ slots,
                                const float* __restrict__ oldmm,
                                float* __restrict__ outc) {
  if (threadIdx.x == 0) {
    float clo = funmono(slots[0]), chi = funmono(slots[1]);
    float o0 = oldmm[0], o1 = oldmm[1];
    bool fin = isfinite(o0) && isfinite(o1);
    float lo = fin ? (0.9f * o0 + 0.1f * clo) : clo;
    float hi = fin ? (0.9f * o1 + 0.1f * chi) : chi;
    float sc = (hi - lo) / 255.0f;
    outc[0] = lo;
    outc[1] = hi;
    outc[2] = sc;
    outc[3] = 0.02004f * fmaxf(fabsf(lo), fabsf(hi));
    outc[4] = 1.0f / sc;
  }
}

__global__ __launch_bounds__(256) void minmax_kernel(const float4* __restrict__ x,
                                                     int n4, unsigned* __restrict__ slots) {
  float lmin = INFINITY, lmax = -INFINITY;
  for (int i = blockIdx.x * blockDim.x + threadIdx.x; i < n4; i += gridDim.x * blockDim.x) {
    float4 a = x[i];
    lmin = fminf(lmin, fminf(fminf(a.x, a.y), fminf(a.z, a.w)));
    lmax = fmaxf(lmax, fmaxf(fmaxf(a.x, a.y), fmaxf(a.z, a.w)));
  }
  __shared__ unsigned bmin, bmax;
  if (threadIdx.x == 0) { bmin = 0xFFFFFFFFu; bmax = 0u; }
  __syncthreads();
  atomicMin(&bmin, fmono(lmin));
  atomicMax(&bmax, fmono(lmax));
  __syncthreads();
  if (threadIdx.x == 0) push_minmax(slots, bmin, bmax);
}

// ---------------- quantization + split prepasses ----------------
__global__ __launch_bounds__(256) void quant_q_kernel(const float* __restrict__ q,
    unsigned short* __restrict__ qnb, unsigned short* __restrict__ qh,
    unsigned short* __restrict__ ql, const float* __restrict__ cw) {
  const float lo = cw[0], hi = cw[1], sc = cw[2];
  int idx = blockIdx.x * 256 + threadIdx.x;
  float4 x = ((const float4*)q)[idx];
  float xa[4] = {x.x, x.y, x.z, x.w};
  ushort4 o, oh, ol;
  unsigned short* op = (unsigned short*)&o;
  unsigned short* ohp = (unsigned short*)&oh;
  unsigned short* olp = (unsigned short*)&ol;
#pragma unroll
  for (int j = 0; j < 4; ++j) {
    float n = rintf((fminf(fmaxf(xa[j], lo), hi) - lo) / sc);
    op[j] = f2bf(n);
    f16split(xa[j], &ohp[j], &olp[j]);
  }
  ((ushort4*)qnb)[idx] = o;
  ((ushort4*)qh)[idx] = oh;
  ((ushort4*)ql)[idx] = ol;
}

__global__ __launch_bounds__(256) void quant_k_kernel(const float* __restrict__ k,
    unsigned short* __restrict__ kzb, unsigned short* __restrict__ kmb,
    unsigned short* __restrict__ kh, unsigned short* __restrict__ kl,
    float* __restrict__ Zk, float* __restrict__ Mk, const float* __restrict__ cw) {
  const float lo = cw[8], hi = cw[9], sc = cw[10], thr = cw[11];
  const int tid = threadIdx.x;
  const int row = blockIdx.x * 8 + (tid >> 5);      // global key row [0, 8*2048)
  const int c4 = (tid & 31) * 4;
  float4 x = *(const float4*)&k[(size_t)row * HD + c4];
  float xa[4] = {x.x, x.y, x.z, x.w};
  ushort4 zo, mo, ho, lo_;
  unsigned short* zp = (unsigned short*)&zo;
  unsigned short* mp = (unsigned short*)&mo;
  unsigned short* hp = (unsigned short*)&ho;
  unsigned short* lp = (unsigned short*)&lo_;
  float zs = 0.f, ms = 0.f;
#pragma unroll
  for (int j = 0; j < 4; ++j) {
    float m = rintf((fminf(fmaxf(xa[j], lo), hi) - lo) / sc);
    float kq = m * sc + lo;
    float z = (fabsf(kq) < thr) ? 0.f : 1.f;
    float mq = z * m;
    zs += z; ms += mq;
    zp[j] = f2bf(z); mp[j] = f2bf(mq);
    f16split(xa[j], &hp[j], &lp[j]);
  }
  *(ushort4*)&kzb[(size_t)row * HD + c4] = zo;
  *(ushort4*)&kmb[(size_t)row * HD + c4] = mo;
  *(ushort4*)&kh[(size_t)row * HD + c4] = ho;
  *(ushort4*)&kl[(size_t)row * HD + c4] = lo_;
#pragma unroll
  for (int off = 16; off > 0; off >>= 1) {
    zs += __shfl_xor(zs, off);
    ms += __shfl_xor(ms, off);
  }
  if ((tid & 31) == 0) { Zk[row] = zs; Mk[row] = ms; }
}

__global__ __launch_bounds__(256) void quant_v_kernel(const float* __restrict__ v,
    unsigned short* __restrict__ vzT, unsigned short* __restrict__ vmT,
    unsigned short* __restrict__ vhT, unsigned short* __restrict__ vlT,
    const float* __restrict__ cw) {
  const float lo = cw[16], hi = cw[17], sc = cw[18], thr = cw[19];
  const int kvh = blockIdx.y, dg = blockIdx.x;   // dg: 0..31 (4 d's each)
  const int tid = threadIdx.x;
  for (int ch = 0; ch < 8; ++ch) {
    int kp = ch * 256 + tid;
    float4 x = *(const float4*)&v[((size_t)(kvh * SEQ + kp)) * HD + dg * 4];
    float xa[4] = {x.x, x.y, x.z, x.w};
#pragma unroll
    for (int j = 0; j < 4; ++j) {
      float m = rintf((fminf(fmaxf(xa[j], lo), hi) - lo) / sc);
      float vq = m * sc + lo;
      float z = (fabsf(vq) < thr) ? 0.f : 1.f;
      float mq = z * m;
      size_t o = ((size_t)(kvh * HD + dg * 4 + j)) * SEQ + kp;
      vzT[o] = f2bf(z);
      vmT[o] = f2bf(mq);
      unsigned short hb, lb;
      f16split(xa[j], &hb, &lb);
      vhT[o] = hb;
      vlT[o] = lb;
    }
  }
}

// ---------------- QK raw min/max via 3-term fp16-split MFMA, LDS-staged B ----------------
__global__ __launch_bounds__(256, 2) void qk_raw_mfma(
    const unsigned short* __restrict__ qh, const unsigned short* __restrict__ ql,
    const unsigned short* __restrict__ kh, const unsigned short* __restrict__ kl,
    unsigned* __restrict__ slots) {
  __shared__ __align__(16) unsigned short s_h[128 * 128];
  __shared__ __align__(16) unsigned short s_l[128 * 128];
  const int kbi = blockIdx.x, qbi = blockIdx.y, h = blockIdx.z;
  const int kvh = h >> 2;
  const int tid = threadIdx.x;
  const int wid = tid >> 6, lane = tid & 63;
  const int fr = lane & 15, fg = lane >> 4;
  const int qrow0 = qbi * 128 + wid * 32;
  const int kcol0 = kbi * 128;
  const unsigned short* qhg = qh + (size_t)h * SEQ * HD;
  const unsigned short* qlg = ql + (size_t)h * SEQ * HD;

  stage_panel(kh + ((size_t)kvh * SEQ + kcol0) * HD, HD, s_h, tid);
  stage_panel(kl + ((size_t)kvh * SEQ + kcol0) * HD, HD, s_l, tid);
  __syncthreads();

  f32x4 acc[2][8];
  const f32x4 z4 = {0.f, 0.f, 0.f, 0.f};
#pragma unroll
  for (int rg = 0; rg < 2; ++rg)
#pragma unroll
    for (int cg = 0; cg < 8; ++cg) acc[rg][cg] = z4;

#pragma unroll
  for (int ks = 0; ks < 4; ++ks) {
    const int d0 = ks * 32 + fg * 8;
    const int c16 = ks * 4 + fg;
    const f16x8 a0h = *(const f16x8*)&qhg[(size_t)(qrow0 + fr) * HD + d0];
    const f16x8 a0l = *(const f16x8*)&qlg[(size_t)(qrow0 + fr) * HD + d0];
    const f16x8 a1h = *(const f16x8*)&qhg[(size_t)(qrow0 + 16 + fr) * HD + d0];
    const f16x8 a1l = *(const f16x8*)&qlg[(size_t)(qrow0 + 16 + fr) * HD + d0];
#pragma unroll
    for (int cg = 0; cg < 8; ++cg) {
      const f16x8 bh = frag_h(s_h, cg * 16 + fr, c16);
      const f16x8 bl = frag_h(s_l, cg * 16 + fr, c16);
      acc[0][cg] = __builtin_amdgcn_mfma_f32_16x16x32_f16(a0h, bh, acc[0][cg], 0, 0, 0);
      acc[0][cg] = __builtin_amdgcn_mfma_f32_16x16x32_f16(a0h, bl, acc[0][cg], 0, 0, 0);
      acc[0][cg] = __builtin_amdgcn_mfma_f32_16x16x32_f16(a0l, bh, acc[0][cg], 0, 0, 0);
      acc[1][cg] = __builtin_amdgcn_mfma_f32_16x16x32_f16(a1h, bh, acc[1][cg], 0, 0, 0);
      acc[1][cg] = __builtin_amdgcn_mfma_f32_16x16x32_f16(a1h, bl, acc[1][cg], 0, 0, 0);
      acc[1][cg] = __builtin_amdgcn_mfma_f32_16x16x32_f16(a1l, bh, acc[1][cg], 0, 0, 0);
    }
  }
  float lmin = INFINITY, lmax = -INFINITY;
#pragma unroll
  for (int rg = 0; rg < 2; ++rg)
#pragma unroll
    for (int cg = 0; cg < 8; ++cg)
#pragma unroll
      for (int r = 0; r < 4; ++r) {
        const float rv = acc[rg][cg][r] * SCALING_F;
        lmin = fminf(lmin, rv);
        lmax = fmaxf(lmax, rv);
      }
  __shared__ unsigned bmin, bmax;
  if (tid == 0) { bmin = 0xFFFFFFFFu; bmax = 0u; }
  __syncthreads();
  atomicMin(&bmin, fmono(lmin));
  atomicMax(&bmax, fmono(lmax));
  __syncthreads();
  if (tid == 0) push_minmax(slots, bmin, bmax);
}

// ---------------- QK quant (bf16 MFMA, exact integer grid), LDS-staged B ----------------
__global__ __launch_bounds__(256, 2) void qk_quant_kernel(
    const unsigned short* __restrict__ qnb, const unsigned short* __restrict__ kzb,
    const unsigned short* __restrict__ kmb, const float* __restrict__ Zk,
    const float* __restrict__ Mk, float* __restrict__ qdot,
    const float* __restrict__ cw) {
  const int kbi = blockIdx.x, qbi = blockIdx.y, h = blockIdx.z;
  if (kbi > qbi) return;            // raw-only region above the diagonal
  __shared__ __align__(16) unsigned short s_z[128 * 128];
  __shared__ __align__(16) unsigned short s_m[128 * 128];
  const int kvh = h >> 2;
  const float qlo = cw[0], qsc = cw[2];
  const float klo = cw[8], ksc = cw[10];
  const int tid = threadIdx.x;
  const int wid = tid >> 6, lane = tid & 63;
  const int fr = lane & 15, fg = lane >> 4;
  const int qrow0 = qbi * 128 + wid * 32;
  const int kcol0 = kbi * 128;
  const unsigned short* qg = qnb + (size_t)h * SEQ * HD;

  stage_panel(kzb + ((size_t)kvh * SEQ + kcol0) * HD, HD, s_z, tid);
  stage_panel(kmb + ((size_t)kvh * SEQ + kcol0) * HD, HD, s_m, tid);
  __syncthreads();

  f32x4 P[2][8], R[2][8];
  const f32x4 z4 = {0.f, 0.f, 0.f, 0.f};
#pragma unroll
  for (int rg = 0; rg < 2; ++rg)
#pragma unroll
    for (int cg = 0; cg < 8; ++cg) { P[rg][cg] = z4; R[rg][cg] = z4; }

#pragma unroll
  for (int ks = 0; ks < 4; ++ks) {
    const int d0 = ks * 32 + fg * 8;
    const int c16 = ks * 4 + fg;
    const bf16x8 a0 = *(const bf16x8*)&qg[(size_t)(qrow0 + fr) * HD + d0];
    const bf16x8 a1 = *(const bf16x8*)&qg[(size_t)(qrow0 + 16 + fr) * HD + d0];
#pragma unroll
    for (int cg = 0; cg < 8; ++cg) {
      const bf16x8 bz = frag_b(s_z, cg * 16 + fr, c16);
      const bf16x8 bm = frag_b(s_m, cg * 16 + fr, c16);
      P[0][cg] = __builtin_amdgcn_mfma_f32_16x16x32_bf16(a0, bz, P[0][cg], 0, 0, 0);
      P[1][cg] = __builtin_amdgcn_mfma_f32_16x16x32_bf16(a1, bz, P[1][cg], 0, 0, 0);
      R[0][cg] = __builtin_amdgcn_mfma_f32_16x16x32_bf16(a0, bm, R[0][cg], 0, 0, 0);
      R[1][cg] = __builtin_amdgcn_mfma_f32_16x16x32_bf16(a1, bm, R[1][cg], 0, 0, 0);
    }
  }
#pragma unroll
  for (int cg = 0; cg < 8; ++cg) {
    const int col = kcol0 + cg * 16 + fr;
    const float Z = Zk[kvh * SEQ + col], M = Mk[kvh * SEQ + col];
    const float base = qlo * (klo * Z + ksc * M);
#pragma unroll
    for (int rg = 0; rg < 2; ++rg)
#pragma unroll
      for (int r = 0; r < 4; ++r) {
        const int row = qrow0 + rg * 16 + fg * 4 + r;
        qdot[((size_t)h * SEQ + row) * SEQ + col] =
            base + qsc * (klo * P[rg][cg][r] + ksc * R[rg][cg][r]);
      }
  }
}

// ---------------- softmax: causal skip + stoch-quant + softmax ----------------
__global__ __launch_bounds__(256) void softmax_kernel(
    float* __restrict__ attn, const float* __restrict__ cw,
    unsigned* __restrict__ slots, uint32_t uk0, uint32_t uk1) {
  const int row = blockIdx.x;          // h*SEQ + qi
  const int qi = row & (SEQ - 1);
  const int tid = threadIdx.x;
  const float lo = cw[24], hi = cw[25], sc = cw[26], sci = cw[28];
  float* prow = attn + (size_t)row * SEQ;
  const uint32_t jbase = (uint32_t)row << 11;

  float vals[8];
  float lmax = -INFINITY;
#pragma unroll
  for (int m = 0; m < 2; ++m) {
    int ki = m * 1024 + tid * 4;
    if (ki <= qi) {
      float4 x4 = *(const float4*)&prow[ki];
      float xa[4] = {x4.x, x4.y, x4.z, x4.w};
#pragma unroll
      for (int j = 0; j < 4; ++j) {
        if (ki + j <= qi) {
          float u = tf_uniform(uk0, uk1, jbase + (uint32_t)(ki + j));
          float lg = fq_st_i(xa[j], lo, hi, sc, sci, u) * SCALING_F;
          vals[m * 4 + j] = lg;
          lmax = fmaxf(lmax, lg);
        } else {
          vals[m * 4 + j] = -INFINITY;
        }
      }
    } else {
      vals[m * 4 + 0] = vals[m * 4 + 1] = vals[m * 4 + 2] = vals[m * 4 + 3] = -INFINITY;
    }
  }

  __shared__ float smax[4], ssum[4], smn[4], smx[4];
#pragma unroll
  for (int off = 32; off > 0; off >>= 1) lmax = fmaxf(lmax, __shfl_xor(lmax, off));
  if ((tid & 63) == 0) smax[tid >> 6] = lmax;
  __syncthreads();
  float rmax = fmaxf(fmaxf(smax[0], smax[1]), fmaxf(smax[2], smax[3]));

  float lsum = 0.f;
#pragma unroll
  for (int e = 0; e < 8; ++e) { vals[e] = __expf(vals[e] - rmax); lsum += vals[e]; }
#pragma unroll
  for (int off = 32; off > 0; off >>= 1) lsum += __shfl_xor(lsum, off);
  if ((tid & 63) == 0) ssum[tid >> 6] = lsum;
  __syncthreads();
  float rinv = 1.0f / (ssum[0] + ssum[1] + ssum[2] + ssum[3]);

  float lmin2 = INFINITY, lmax2 = -INFINITY;
#pragma unroll
  for (int m = 0; m < 2; ++m) {
    int ki = m * 1024 + tid * 4;
    float4 st;
    float* stp = (float*)&st;
#pragma unroll
    for (int j = 0; j < 4; ++j) {
      float w = vals[m * 4 + j] * rinv;
      stp[j] = w;
      lmin2 = fminf(lmin2, w);
      lmax2 = fmaxf(lmax2, w);
    }
    *(float4*)&prow[ki] = st;
  }
#pragma unroll
  for (int off = 32; off > 0; off >>= 1) {
    lmin2 = fminf(lmin2, __shfl_xor(lmin2, off));
    lmax2 = fmaxf(lmax2, __shfl_xor(lmax2, off));
  }
  if ((tid & 63) == 0) { smn[tid >> 6] = lmin2; smx[tid >> 6] = lmax2; }
  __syncthreads();
  if (tid == 0) {
    float mn = fminf(fminf(smn[0], smn[1]), fminf(smn[2], smn[3]));
    float mx = fmaxf(fmaxf(smx[0], smx[1]), fmaxf(smx[2], smx[3]));
    push_minmax(slots, fmono(mn), fmono(mx));
  }
}

// ---------------- AV raw min/max via 3-term fp16-split MFMA, LDS-staged V ----------------
__device__ __forceinline__ void pack_split8(const float* __restrict__ p,
                                            f16x8* ah, f16x8* al) {
  float4 w0 = *(const float4*)p;
  float4 w1 = *(const float4*)(p + 4);
  float wa[8] = {w0.x, w0.y, w0.z, w0.w, w1.x, w1.y, w1.z, w1.w};
  f16x8 h, l;
#pragma unroll
  for (int j = 0; j < 8; ++j) {
    _Float16 hf = (_Float16)wa[j];
    h[j] = hf;
    l[j] = (_Float16)(wa[j] - (float)hf);
  }
  *ah = h; *al = l;
}

__global__ __launch_bounds__(256, 2) void av_raw_mfma(
    const float* __restrict__ attn, const unsigned short* __restrict__ vhT,
    const unsigned short* __restrict__ vlT, unsigned* __restrict__ slots) {
  __shared__ __align__(16) unsigned short s_h[128 * 128];
  __shared__ __align__(16) unsigned short s_l[128 * 128];
  const int qbi = (int)gridDim.x - 1 - (int)blockIdx.x;  // largest blocks first
  const int h = blockIdx.y, kvh = h >> 2;
  const int tid = threadIdx.x;
  const int wid = tid >> 6, lane = tid & 63;
  const int fr = lane & 15, fg = lane >> 4;
  const int qrow0 = qbi * 128 + wid * 32;
  const float* ag = attn + (size_t)h * SEQ * SEQ;
  const unsigned short* bhg = vhT + (size_t)kvh * HD * SEQ;
  const unsigned short* blg = vlT + (size_t)kvh * HD * SEQ;
  const int nc = qbi + 1;   // 128-kp chunks; beyond qb+127 attn is exactly 0
  f32x4 acc[2][8];
  const f32x4 z4 = {0.f, 0.f, 0.f, 0.f};
#pragma unroll
  for (int rg = 0; rg < 2; ++rg)
#pragma unroll
    for (int cg = 0; cg < 8; ++cg) acc[rg][cg] = z4;

  for (int c = 0; c < nc; ++c) {
    __syncthreads();
    stage_panel(bhg + c * 128, SEQ, s_h, tid);   // [d][kp] chunk, rows=d
    stage_panel(blg + c * 128, SEQ, s_l, tid);
    __syncthreads();
#pragma unroll
    for (int ks = 0; ks < 4; ++ks) {
      const int kp0 = c * 128 + ks * 32 + fg * 8;
      const int c16 = ks * 4 + fg;
      f16x8 a0h, a0l, a1h, a1l;
      pack_split8(ag + (size_t)(qrow0 + fr) * SEQ + kp0, &a0h, &a0l);
      pack_split8(ag + (size_t)(qrow0 + 16 + fr) * SEQ + kp0, &a1h, &a1l);
#pragma unroll
      for (int cg = 0; cg < 8; ++cg) {
        const f16x8 bh = frag_h(s_h, cg * 16 + fr, c16);
        const f16x8 bl = frag_h(s_l, cg * 16 + fr, c16);
        acc[0][cg] = __builtin_amdgcn_mfma_f32_16x16x32_f16(a0h, bh, acc[0][cg], 0, 0, 0);
        acc[0][cg] = __builtin_amdgcn_mfma_f32_16x16x32_f16(a0h, bl, acc[0][cg], 0, 0, 0);
        acc[0][cg] = __builtin_amdgcn_mfma_f32_16x16x32_f16(a0l, bh, acc[0][cg], 0, 0, 0);
        acc[1][cg] = __builtin_amdgcn_mfma_f32_16x16x32_f16(a1h, bh, acc[1][cg], 0, 0, 0);
        acc[1][cg] = __builtin_amdgcn_mfma_f32_16x16x32_f16(a1h, bl, acc[1][cg], 0, 0, 0);
        acc[1][cg] = __builtin_amdgcn_mfma_f32_16x16x32_f16(a1l, bh, acc[1][cg], 0, 0, 0);
      }
    }
  }
  float lmin = INFINITY, lmax = -INFINITY;
#pragma unroll
  for (int rg = 0; rg < 2; ++rg)
#pragma unroll
    for (int cg = 0; cg < 8; ++cg)
#pragma unroll
      for (int r = 0; r < 4; ++r) {
        lmin = fminf(lmin, acc[rg][cg][r]);
        lmax = fmaxf(lmax, acc[rg][cg][r]);
      }
  __shared__ unsigned bmin, bmax;
  if (tid == 0) { bmin = 0xFFFFFFFFu; bmax = 0u; }
  __syncthreads();
  atomicMin(&bmin, fmono(lmin));
  atomicMax(&bmax, fmono(lmax));
  __syncthreads();
  if (tid == 0) push_minmax(slots, bmin, bmax);
}

// ---------------- AV quant (bf16 MFMA), LDS-staged V ----------------
__device__ __forceinline__ bf16x8 pack_a8(const float* __restrict__ ar,
                                          float lo, float hi, float sc) {
  float4 w0 = *(const float4*)ar;
  float4 w1 = *(const float4*)(ar + 4);
  float wa[8] = {w0.x, w0.y, w0.z, w0.w, w1.x, w1.y, w1.z, w1.w};
  bf16x8 r;
#pragma unroll
  for (int j = 0; j < 8; ++j) {
    float n = rintf((fminf(fmaxf(wa[j], lo), hi) - lo) / sc);
    r[j] = (short)(__float_as_uint(n) >> 16);
  }
  return r;
}

__global__ __launch_bounds__(256, 2) void av_quant_kernel(
    const float* __restrict__ attn, const unsigned short* __restrict__ vzT,
    const unsigned short* __restrict__ vmT, float* __restrict__ out0,
    const float* __restrict__ cw) {
  __shared__ __align__(16) unsigned short s_z[128 * 128];
  __shared__ __align__(16) unsigned short s_m[128 * 128];
  const int qbi = (int)gridDim.x - 1 - (int)blockIdx.x;
  const int h = blockIdx.y, kvh = h >> 2;
  const float alo = cw[32], ahi = cw[33], asc = cw[34];
  const float vlo = cw[16], vsc = cw[18];
  const int tid = threadIdx.x;
  const int wid = tid >> 6, lane = tid & 63;
  const int fr = lane & 15, fg = lane >> 4;
  const int qrow0 = qbi * 128 + wid * 32;
  const float* ag = attn + (size_t)h * SEQ * SEQ;
  const unsigned short* zg = vzT + (size_t)kvh * HD * SEQ;
  const unsigned short* mg = vmT + (size_t)kvh * HD * SEQ;
  const int nc = qbi + 1;
  f32x4 P[2][8], R[2][8];
  const f32x4 z4 = {0.f, 0.f, 0.f, 0.f};
#pragma unroll
  for (int rg = 0; rg < 2; ++rg)
#pragma unroll
    for (int cg = 0; cg < 8; ++cg) { P[rg][cg] = z4; R[rg][cg] = z4; }

  for (int c = 0; c < nc; ++c) {
    __syncthreads();
    stage_panel(zg + c * 128, SEQ, s_z, tid);
    stage_panel(mg + c * 128, SEQ, s_m, tid);
    __syncthreads();
#pragma unroll
    for (int ks = 0; ks < 4; ++ks) {
      const int kp0 = c * 128 + ks * 32 + fg * 8;
      const int c16 = ks * 4 + fg;
      const bf16x8 a0 = pack_a8(ag + (size_t)(qrow0 + fr) * SEQ + kp0, alo, ahi, asc);
      const bf16x8 a1 = pack_a8(ag + (size_t)(qrow0 + 16 + fr) * SEQ + kp0, alo, ahi, asc);
#pragma unroll
      for (int cg = 0; cg < 8; ++cg) {
        const bf16x8 bz = frag_b(s_z, cg * 16 + fr, c16);
        const bf16x8 bm = frag_b(s_m, cg * 16 + fr, c16);
        P[0][cg] = __builtin_amdgcn_mfma_f32_16x16x32_bf16(a0, bz, P[0][cg], 0, 0, 0);
        P[1][cg] = __builtin_amdgcn_mfma_f32_16x16x32_bf16(a1, bz, P[1][cg], 0, 0, 0);
        R[0][cg] = __builtin_amdgcn_mfma_f32_16x16x32_bf16(a0, bm, R[0][cg], 0, 0, 0);
        R[1][cg] = __builtin_amdgcn_mfma_f32_16x16x32_bf16(a1, bm, R[1][cg], 0, 0, 0);
      }
    }
  }
#pragma unroll
  for (int cg = 0; cg < 8; ++cg) {
    const int dcol = cg * 16 + fr;
#pragma unroll
    for (int rg = 0; rg < 2; ++rg)
#pragma unroll
      for (int r = 0; r < 4; ++r) {
        const int row = qrow0 + rg * 16 + fg * 4 + r;
        out0[((size_t)row * NH + h) * HD + dcol] =
            asc * (vlo * P[rg][cg][r] + vsc * R[rg][cg][r]);
      }
  }
}

// ---------------- final elementwise stochastic quantization of out0 ----------------
__global__ __launch_bounds__(256) void stoch_kernel(float* __restrict__ out0,
                                                    const float* __restrict__ cw,
                                                    uint32_t uk0, uint32_t uk1) {
  int idx = blockIdx.x * 256 + threadIdx.x;
  const float lo = cw[40], hi = cw[41], sc = cw[42], sci = cw[44];
  int qi = idx >> 12;                 // / (NH*HD)
  int rem = idx & 4095;
  int h = rem >> 7, d = rem & 127;
  uint32_t j = ((uint32_t)h * SEQ + (uint32_t)qi) * HD + (uint32_t)d;  // BHSD flat
  float x = out0[idx];
  float u = tf_uniform(uk0, uk1, j);
  out0[idx] = fq_st_i(x, lo, hi, sc, sci, u);
}

// ---------------- launcher ----------------
extern "C" void kernel_launch(void* const* d_in, const int* in_sizes, int n_in,
                              void* d_out, int out_size, void* d_ws, size_t ws_size,
                              hipStream_t stream) {
  (void)in_sizes; (void)n_in; (void)out_size; (void)ws_size;
  const float* q      = (const float*)d_in[0];
  const float* k      = (const float*)d_in[1];
  const float* v      = (const float*)d_in[2];
  const float* q_old  = (const float*)d_in[4];
  const float* k_old  = (const float*)d_in[5];
  const float* qk_old = (const float*)d_in[6];
  const float* a_old  = (const float*)d_in[7];
  const float* v_old  = (const float*)d_in[8];
  const float* av_old = (const float*)d_in[9];
  float* out0 = (float*)d_out;
  float* out1 = out0 + (size_t)OUT0_N;
  unsigned* su = (unsigned*)d_ws;
  float* cw = (float*)d_ws + 16;

  // d_ws scratch: vzT/vmT (live until av_quant), Zk/Mk  (~8.5 MB)
  unsigned short* vzT = (unsigned short*)((char*)d_ws + 1024);
  unsigned short* vmT = vzT + (size_t)NKVH * SEQ * HD;
  float* Zk = (float*)(vmT + (size_t)NKVH * SEQ * HD);
  float* Mk = Zk + NKVH * SEQ;

  // out0-region scratch (exactly fills 32 MB; all consumed before av_quant
  // overwrites out0): qnb(16MB) kzb(4MB) kmb(4MB) vhT(4MB) vlT(4MB)
  unsigned short* qnb = (unsigned short*)out0;
  unsigned short* kzb = qnb + (size_t)NH * SEQ * HD;
  unsigned short* kmb = kzb + (size_t)NKVH * SEQ * HD;
  unsigned short* vhT = kmb + (size_t)NKVH * SEQ * HD;
  unsigned short* vlT = vhT + (size_t)NKVH * SEQ * HD;

  // out1-region scratch (consumed by qk_raw_mfma BEFORE qk_quant writes out1;
  // in-order stream guarantees ordering): qh/ql (16MB ea), kh/kl (4MB ea)
  unsigned short* qh = (unsigned short*)out1;
  unsigned short* ql = qh + (size_t)NH * SEQ * HD;
  unsigned short* kh = ql + (size_t)NH * SEQ * HD;
  unsigned short* kl = kh + (size_t)NKVH * SEQ * HD;

  uint32_t kq0, kq1, ka0, ka1;
  tf2x32(0u, 0u, 0u, 0u, &kq0, &kq1);
  tf2x32(0u, 0u, 0u, 1u, &ka0, &ka1);

  init_ws<<<1, 32, 0, stream>>>(su);
  minmax_kernel<<<1024, 256, 0, stream>>>((const float4*)q, (NH * SEQ * HD) / 4, su + 0);
  minmax_kernel<<<512, 256, 0, stream>>>((const float4*)k, (NKVH * SEQ * HD) / 4, su + 2);
  minmax_kernel<<<512, 256, 0, stream>>>((const float4*)v, (NKVH * SEQ * HD) / 4, su + 4);
  finalize_kernel<<<1, 1, 0, stream>>>(su + 0, q_old, cw + 0);
  finalize_kernel<<<1, 1, 0, stream>>>(su + 2, k_old, cw + 8);
  finalize_kernel<<<1, 1, 0, stream>>>(su + 4, v_old, cw + 16);

  quant_q_kernel<<<(NH * SEQ * HD) / 4 / 256, 256, 0, stream>>>(q, qnb, qh, ql, cw);
  quant_k_kernel<<<(NKVH * SEQ) / 8, 256, 0, stream>>>(k, kzb, kmb, kh, kl, Zk, Mk, cw);
  quant_v_kernel<<<dim3(32, NKVH), 256, 0, stream>>>(v, vzT, vmT, vhT, vlT, cw);

  qk_raw_mfma<<<dim3(16, 16, NH), 256, 0, stream>>>(qh, ql, kh, kl, su + 6);
  finalize_kernel<<<1, 1, 0, stream>>>(su + 6, qk_old, cw + 24);
  qk_quant_kernel<<<dim3(16, 16, NH), 256, 0, stream>>>(qnb, kzb, kmb, Zk, Mk, out1, cw);

  softmax_kernel<<<NH * SEQ, 256, 0, stream>>>(out1, cw, su + 8, kq0, kq1);
  finalize_kernel<<<1, 1, 0, stream>>>(su + 8, a_old, cw + 32);

  av_raw_mfma<<<dim3(16, NH), 256, 0, stream>>>(out1, vhT, vlT, su + 10);
  finalize_kernel<<<1, 1, 0, stream>>>(su + 10, av_old, cw + 40);
  av_quant_kernel<<<dim3(16, NH), 256, 0, stream>>>(out1, vzT, vmT, out0, cw);

  stoch_kernel<<<OUT0_N / 256, 256, 0, stream>>>(out0, cw, ka0, ka1);
}